// Round 2
// baseline (340.489 us; speedup 1.0000x reference)
//
#include <hip/hip_runtime.h>
#include <hip/hip_bf16.h>

#define N_ATOMS 8192
#define N_PAIR  131072
#define F       128
#define N_HEAD  8
#define FH      16
#define N_DEG   3
#define M_TOT   15
#define K_RBF   32
#define H_FILT  64
#define FILT_OUT 768
#define NDH     24   // N_DEG * N_HEAD

typedef __attribute__((ext_vector_type(8))) unsigned short u16x8;

__device__ __forceinline__ float bf2f(unsigned short u) {
    return __uint_as_float(((unsigned)u) << 16);
}
__device__ __forceinline__ unsigned short f2bfbits(float f) {
    __hip_bfloat16 b = __float2bfloat16(f);
    return *reinterpret_cast<unsigned short*>(&b);
}

// ---------------- K0: segment starts (idx_i is sorted) ----------------
__global__ void k_seg(const int* __restrict__ idx_i, int* __restrict__ row_start) {
    int p = blockIdx.x * 256 + threadIdx.x;
    if (p >= N_PAIR) return;
    int ii = idx_i[p];
    int prev = (p == 0) ? -1 : idx_i[p - 1];
    for (int a = prev + 1; a <= ii; ++a) row_start[a] = p;
    if (p == N_PAIR - 1) {
        for (int a = ii + 1; a <= N_ATOMS; ++a) row_start[a] = N_PAIR;
    }
}

// ---------------- zero counters (graph-replay safe) ----------------
__global__ void k_zero(int* __restrict__ counts, int* __restrict__ cnt2) {
    int t = blockIdx.x * 256 + threadIdx.x;
    if (t < N_ATOMS) { counts[t] = 0; cnt2[t] = 0; }
}

// ---------------- histogram of idx_j ----------------
__global__ void k_hist(const int* __restrict__ idx_j, int* __restrict__ counts) {
    int p = blockIdx.x * 256 + threadIdx.x;
    if (p < N_PAIR) atomicAdd(&counts[idx_j[p]], 1);
}

// ---------------- exclusive scan of 8192 counts (1 block) ----------------
__global__ __launch_bounds__(1024) void k_scan(const int* __restrict__ counts,
                                               int* __restrict__ offsets) {
    __shared__ int ts[1024];
    int tid = threadIdx.x;
    int base = tid * 8;
    int v[8]; int tot = 0;
    #pragma unroll
    for (int q = 0; q < 8; ++q) { v[q] = counts[base + q]; tot += v[q]; }
    ts[tid] = tot; __syncthreads();
    for (int off = 1; off < 1024; off <<= 1) {
        int t2 = (tid >= off) ? ts[tid - off] : 0;
        __syncthreads();
        ts[tid] += t2;
        __syncthreads();
    }
    int excl = ts[tid] - tot;
    #pragma unroll
    for (int q = 0; q < 8; ++q) { offsets[base + q] = excl; excl += v[q]; }
    if (tid == 1023) offsets[N_ATOMS] = ts[1023];
}

// ---------------- placement: sorted pair ids per j-bucket ----------------
__global__ void k_place(const int* __restrict__ idx_j, const int* __restrict__ offsets,
                        int* __restrict__ cnt2, int* __restrict__ sorted) {
    int p = blockIdx.x * 256 + threadIdx.x;
    if (p < N_PAIR) {
        int j = idx_j[p];
        int pos = offsets[j] + atomicAdd(&cnt2[j], 1);
        sorted[pos] = p;
    }
}

// ---------------- K1a: Qa[n,dhc] = Q[n,d,h,c]*a_q[d,h,c]; Ka likewise (bf16) ----------------
__global__ __launch_bounds__(256) void k_qa(
    const float* __restrict__ x, const float* __restrict__ WQ,
    const float* __restrict__ WK, const float* __restrict__ avec,
    __hip_bfloat16* __restrict__ Qa, __hip_bfloat16* __restrict__ Ka)
{
    __shared__ float wq_l[N_DEG * N_HEAD * FH * FH]; // 6144
    __shared__ float wk_l[N_DEG * N_HEAD * FH * FH]; // 6144
    __shared__ float a_l[N_DEG * N_HEAD * 32];       // 768
    __shared__ float x_l[8][F];                      // 1024
    int tid = threadIdx.x;
    for (int e = tid; e < 6144; e += 256) { wq_l[e] = WQ[e]; wk_l[e] = WK[e]; }
    for (int e = tid; e < 768; e += 256) a_l[e] = avec[e];
    int n0 = blockIdx.x * 8;
    for (int e = tid; e < 8 * F; e += 256)
        x_l[e >> 7][e & 127] = x[(size_t)(n0 + (e >> 7)) * F + (e & 127)];
    __syncthreads();
    for (int o = tid; o < 8 * 768; o += 256) {
        int at = o / 768; int r = o % 768;
        int side = r / 384; int dhc = r % 384;
        int dh = dhc >> 4;
        const float* Wl = (side == 0) ? wq_l : wk_l;
        int xb = (dh & 7) * 16; // h*16
        float s = 0.f;
        #pragma unroll
        for (int jj = 0; jj < 16; ++jj) s += Wl[dhc * 16 + jj] * x_l[at][xb + jj];
        int c = dhc & 15;
        float av = a_l[dh * 32 + (side << 4) + c];
        __hip_bfloat16* Out = (side == 0) ? Qa : Ka;
        Out[(size_t)(n0 + at) * 384 + dhc] = __float2bfloat16(s * av);
    }
}

// ---------------- K1b: Gq[n,dh,k] = sum_c W2[k,col]*Qa[n,dhc]; bq = b2 dot ----------------
__global__ __launch_bounds__(256) void k_g(
    const __hip_bfloat16* __restrict__ Qa, const __hip_bfloat16* __restrict__ Ka,
    const float* __restrict__ W2, const float* __restrict__ b2,
    __hip_bfloat16* __restrict__ Gq, __hip_bfloat16* __restrict__ Gk,
    float* __restrict__ bq, float* __restrict__ bk)
{
    __shared__ float w2s[H_FILT][FH]; // 64x16
    __shared__ float qas[64][FH];     // 64 atoms x 16
    __shared__ float b2s[FH];
    int tid = threadIdx.x;
    int n0 = blockIdx.x * 64;
    int sdh = blockIdx.y;            // 0..47
    int side = sdh / NDH, dh = sdh % NDH;
    int d = dh >> 3, h = dh & 7;
    int colbase = d * 256 + h * 32 + side * 16;
    const __hip_bfloat16* Src = (side == 0) ? Qa : Ka;
    for (int e = tid; e < 64 * 16; e += 256) {
        int k = e >> 4, c = e & 15;
        w2s[k][c] = W2[k * FILT_OUT + colbase + c];
    }
    for (int e = tid; e < 64 * 16; e += 256) {
        int at = e >> 4, c = e & 15;
        qas[at][c] = __bfloat162float(Src[(size_t)(n0 + at) * 384 + dh * 16 + c]);
    }
    if (tid < 16) b2s[tid] = b2[colbase + tid];
    __syncthreads();
    __hip_bfloat16* G = (side == 0) ? Gq : Gk;
    float* B = (side == 0) ? bq : bk;
    for (int o = tid; o < 64 * 64; o += 256) {
        int at = o >> 6, k = o & 63;
        float s = 0.f;
        #pragma unroll
        for (int c = 0; c < 16; ++c) s += qas[at][c] * w2s[k][c];
        G[(size_t)(n0 + at) * 1536 + dh * 64 + k] = __float2bfloat16(s);
        if (k == 0) {
            float sb = 0.f;
            #pragma unroll
            for (int c = 0; c < 16; ++c) sb += qas[at][c] * b2s[c];
            B[(n0 + at) * NDH + dh] = sb;
        }
    }
}

// ---------------- K2a: h1[p,64] = silu(rbf @ W1 + b1), bf16 ----------------
__global__ __launch_bounds__(256) void k_h1(
    const float* __restrict__ rbf, const float* __restrict__ W1,
    const float* __restrict__ b1, unsigned short* __restrict__ h1)
{
    __shared__ float w1s[K_RBF][H_FILT]; // 8 KB
    __shared__ float b1s[H_FILT];
    __shared__ float rbfs[64][33];       // padded
    int tid = threadIdx.x;
    int p0 = blockIdx.x * 64;
    for (int e = tid; e < K_RBF * H_FILT; e += 256) w1s[e >> 6][e & 63] = W1[e];
    if (tid < H_FILT) b1s[tid] = b1[tid];
    for (int e = tid; e < 64 * K_RBF; e += 256)
        rbfs[e >> 5][e & 31] = rbf[(size_t)p0 * K_RBF + e];
    __syncthreads();
    int pp = tid >> 2;
    int kbase = (tid & 3) * 16;
    float acc[16];
    #pragma unroll
    for (int q = 0; q < 16; ++q) acc[q] = b1s[kbase + q];
    for (int c = 0; c < K_RBF; ++c) {
        float r = rbfs[pp][c];
        #pragma unroll
        for (int q = 0; q < 16; ++q) acc[q] += r * w1s[c][kbase + q];
    }
    u16x8 o0, o1;
    #pragma unroll
    for (int q = 0; q < 8; ++q) {
        float s0 = acc[q];     o0[q] = f2bfbits(s0 / (1.f + __expf(-s0)));
        float s1 = acc[q + 8]; o1[q] = f2bfbits(s1 / (1.f + __expf(-s1)));
    }
    unsigned short* hp = h1 + (size_t)(p0 + pp) * 64 + kbase;
    *reinterpret_cast<u16x8*>(hp) = o0;
    *reinterpret_cast<u16x8*>(hp + 8) = o1;
}

// ---------------- K2b: Q-side alpha (pair-major, idx_i sorted => cached Gq) ----------------
__global__ __launch_bounds__(256) void k_alpha_q(
    const int* __restrict__ idx_i,
    const unsigned short* __restrict__ h1,
    const __hip_bfloat16* __restrict__ Gq, const float* __restrict__ bq,
    float* __restrict__ alpha)
{
    __shared__ unsigned short h1s[8][64];
    int tid = threadIdx.x;
    int p0 = blockIdx.x * 8;
    if (tid < 64) {
        int pp = tid >> 3, seg = tid & 7;
        *reinterpret_cast<u16x8*>(&h1s[pp][seg * 8]) =
            *reinterpret_cast<const u16x8*>(h1 + (size_t)(p0 + pp) * 64 + seg * 8);
    }
    __syncthreads();
    int pp = tid >> 5, lane = tid & 31;
    if (lane < NDH) {
        int p = p0 + pp;
        int i = idx_i[p];
        float acc = bq[i * NDH + lane];
        const __hip_bfloat16* gq = Gq + (size_t)i * 1536 + lane * 64;
        #pragma unroll
        for (int v = 0; v < 8; ++v) {
            u16x8 qv = *reinterpret_cast<const u16x8*>(gq + v * 8);
            u16x8 hv = *reinterpret_cast<const u16x8*>(&h1s[pp][v * 8]);
            #pragma unroll
            for (int e = 0; e < 8; ++e) acc += bf2f(qv[e]) * bf2f(hv[e]);
        }
        alpha[(size_t)p * NDH + lane] = acc;
    }
}

// ---------------- K2c: K-side alpha (j-bucketed: Gk streamed once) ----------------
__global__ __launch_bounds__(256) void k_alpha_k(
    const int* __restrict__ sorted, const int* __restrict__ offsets,
    const unsigned short* __restrict__ h1,
    const __hip_bfloat16* __restrict__ Gk, const float* __restrict__ bk,
    const float* __restrict__ phi, const float* __restrict__ mask,
    float* __restrict__ alpha)
{
    __shared__ unsigned short h1s[8][64];
    int j = blockIdx.x;
    int s = offsets[j], e = offsets[j + 1];
    if (s == e) return;
    int tid = threadIdx.x;
    int pp = tid >> 5, lane = tid & 31;
    float bkj = (lane < NDH) ? bk[j * NDH + lane] : 0.f;
    const __hip_bfloat16* gk = Gk + (size_t)j * 1536 + lane * 64;
    for (int c0 = s; c0 < e; c0 += 8) {
        int nb = min(8, e - c0);
        __syncthreads();
        if (tid < 64) {
            int sp = tid >> 3, seg = tid & 7;
            if (sp < nb) {
                int pid = sorted[c0 + sp];
                *reinterpret_cast<u16x8*>(&h1s[sp][seg * 8]) =
                    *reinterpret_cast<const u16x8*>(h1 + (size_t)pid * 64 + seg * 8);
            }
        }
        __syncthreads();
        if (lane < NDH && pp < nb) {
            int p = sorted[c0 + pp];
            float acc = 0.f;
            #pragma unroll
            for (int v = 0; v < 8; ++v) {
                u16x8 kv = *reinterpret_cast<const u16x8*>(gk + v * 8);
                u16x8 hv = *reinterpret_cast<const u16x8*>(&h1s[pp][v * 8]);
                #pragma unroll
                for (int ee = 0; ee < 8; ++ee) acc += bf2f(kv[ee]) * bf2f(hv[ee]);
            }
            size_t ai = (size_t)p * NDH + lane;
            float aprev = alpha[ai];
            alpha[ai] = (aprev + acc + bkj) * phi[p] * mask[p] * 0.25f;
        }
    }
}

// ---------------- K3: per-atom segment aggregation ----------------
__global__ __launch_bounds__(128) void k_aggr(
    const float* __restrict__ x, const float* __restrict__ sph,
    const float* __restrict__ mask, const int* __restrict__ idx_j,
    const float* __restrict__ alpha, const int* __restrict__ row_start,
    float* __restrict__ out)
{
    int i = blockIdx.x;
    int tid = threadIdx.x; // f = tid, 128 threads
    int h = tid >> 4;
    float acc[M_TOT];
    #pragma unroll
    for (int m = 0; m < M_TOT; ++m) acc[m] = 0.f;
    int pstart = row_start[i], pend = row_start[i + 1];
    __shared__ float al[8][NDH];
    __shared__ float sl[8][M_TOT];
    __shared__ float xml[8];
    __shared__ int   jl[8];
    for (int pc = pstart; pc < pend; pc += 8) {
        int nb = min(8, pend - pc);
        __syncthreads();
        for (int e = tid; e < nb * NDH; e += 128)
            al[e / NDH][e % NDH] = alpha[(size_t)(pc + e / NDH) * NDH + e % NDH];
        for (int e = tid; e < nb * M_TOT; e += 128)
            sl[e / M_TOT][e % M_TOT] = sph[(size_t)(pc + e / M_TOT) * M_TOT + e % M_TOT];
        if (tid < nb) { xml[tid] = mask[pc + tid]; jl[tid] = idx_j[pc + tid]; }
        __syncthreads();
        for (int q = 0; q < nb; ++q) {
            int j = jl[q];
            float xv = x[(size_t)j * F + tid] * xml[q];
            float c0 = al[q][0 + h], c1 = al[q][8 + h], c2 = al[q][16 + h];
            #pragma unroll
            for (int m = 0; m < 3; ++m)  acc[m] += c0 * sl[q][m] * xv;
            #pragma unroll
            for (int m = 3; m < 8; ++m)  acc[m] += c1 * sl[q][m] * xv;
            #pragma unroll
            for (int m = 8; m < 15; ++m) acc[m] += c2 * sl[q][m] * xv;
        }
    }
    size_t ob = (size_t)i * (M_TOT * F) + tid;
    #pragma unroll
    for (int m = 0; m < M_TOT; ++m) out[ob + m * F] = acc[m];
}

extern "C" void kernel_launch(void* const* d_in, const int* in_sizes, int n_in,
                              void* d_out, int out_size, void* d_ws, size_t ws_size,
                              hipStream_t stream) {
    const float* x     = (const float*)d_in[0];
    const float* rbf   = (const float*)d_in[1];
    const float* sph   = (const float*)d_in[2];
    const float* phi   = (const float*)d_in[3];
    const int*   idx_i = (const int*)d_in[4];
    const int*   idx_j = (const int*)d_in[5];
    const float* mask  = (const float*)d_in[6];
    const float* WQ    = (const float*)d_in[7];
    const float* WK    = (const float*)d_in[8];
    const float* av    = (const float*)d_in[9];
    const float* W1    = (const float*)d_in[10];
    const float* b1    = (const float*)d_in[11];
    const float* W2    = (const float*)d_in[12];
    const float* b2    = (const float*)d_in[13];
    float* out = (float*)d_out;
    char* ws = (char*)d_ws;

    // ws layout (bytes):
    // Qa  bf16 [0,        6291456)   -- dead after k_g; alpha fp32 [0, 12582912) reuses Qa+Ka
    // Ka  bf16 [6291456, 12582912)
    // Gq  bf16 [12582912, 37748736)
    // Gk  bf16 [37748736, 62914560)
    // bq  f32  [62914560, 63700992)
    // bk  f32  [63700992, 64487424)
    // row_start [64487424, 64520448)
    // counts    [64520448, 64553216)
    // offsets   [64553216, 64586240)   (8193 ints)
    // cnt2      [64586240, 64619008)
    // sorted    [64619008, 65143296)
    // h1  bf16  [65143296, 81920512)
    __hip_bfloat16* Qa = (__hip_bfloat16*)(ws + 0);
    __hip_bfloat16* Ka = (__hip_bfloat16*)(ws + 6291456);
    __hip_bfloat16* Gq = (__hip_bfloat16*)(ws + 12582912);
    __hip_bfloat16* Gk = (__hip_bfloat16*)(ws + 37748736);
    float* bq = (float*)(ws + 62914560);
    float* bk = (float*)(ws + 63700992);
    int* row_start = (int*)(ws + 64487424);
    int* counts    = (int*)(ws + 64520448);
    int* offsets   = (int*)(ws + 64553216);
    int* cnt2      = (int*)(ws + 64586240);
    int* sorted    = (int*)(ws + 64619008);
    unsigned short* h1 = (unsigned short*)(ws + 65143296);
    float* alphaBuf = (float*)(ws + 0);

    k_zero<<<(N_ATOMS + 255) / 256, 256, 0, stream>>>(counts, cnt2);
    k_seg<<<(N_PAIR + 255) / 256, 256, 0, stream>>>(idx_i, row_start);
    k_hist<<<(N_PAIR + 255) / 256, 256, 0, stream>>>(idx_j, counts);
    k_scan<<<1, 1024, 0, stream>>>(counts, offsets);
    k_place<<<(N_PAIR + 255) / 256, 256, 0, stream>>>(idx_j, offsets, cnt2, sorted);
    k_qa<<<N_ATOMS / 8, 256, 0, stream>>>(x, WQ, WK, av, Qa, Ka);
    dim3 gg(N_ATOMS / 64, 48);
    k_g<<<gg, 256, 0, stream>>>(Qa, Ka, W2, b2, Gq, Gk, bq, bk);
    k_h1<<<N_PAIR / 64, 256, 0, stream>>>(rbf, W1, b1, h1);
    k_alpha_q<<<N_PAIR / 8, 256, 0, stream>>>(idx_i, h1, Gq, bq, alphaBuf);
    k_alpha_k<<<N_ATOMS, 256, 0, stream>>>(sorted, offsets, h1, Gk, bk, phi, mask, alphaBuf);
    k_aggr<<<N_ATOMS, 128, 0, stream>>>(x, sph, mask, idx_j, alphaBuf, row_start, out);
}

// Round 3
// 239.247 us; speedup vs baseline: 1.4232x; 1.4232x over previous
//
#include <hip/hip_runtime.h>
#include <hip/hip_bf16.h>

#define N_ATOMS 8192
#define N_PAIR  131072
#define F       128
#define N_HEAD  8
#define FH      16
#define N_DEG   3
#define M_TOT   15
#define K_RBF   32
#define H_FILT  64
#define FILT_OUT 768
#define NDH     24   // N_DEG * N_HEAD

typedef __attribute__((ext_vector_type(8))) unsigned short u16x8;

__device__ __forceinline__ float bf2f(unsigned short u) {
    return __uint_as_float(((unsigned)u) << 16);
}
__device__ __forceinline__ unsigned short f2bfbits(float f) {
    __hip_bfloat16 b = __float2bfloat16(f);
    return *reinterpret_cast<unsigned short*>(&b);
}

// ---------------- K0: segment starts (idx_i is sorted) ----------------
__global__ void k_seg(const int* __restrict__ idx_i, int* __restrict__ row_start) {
    int p = blockIdx.x * 256 + threadIdx.x;
    if (p >= N_PAIR) return;
    int ii = idx_i[p];
    int prev = (p == 0) ? -1 : idx_i[p - 1];
    for (int a = prev + 1; a <= ii; ++a) row_start[a] = p;
    if (p == N_PAIR - 1) {
        for (int a = ii + 1; a <= N_ATOMS; ++a) row_start[a] = N_PAIR;
    }
}

// ---------------- zero counters (graph-replay safe) ----------------
__global__ void k_zero(int* __restrict__ counts, int* __restrict__ cnt2) {
    int t = blockIdx.x * 256 + threadIdx.x;
    if (t < N_ATOMS) { counts[t] = 0; cnt2[t] = 0; }
}

// ---------------- histogram of idx_j ----------------
__global__ void k_hist(const int* __restrict__ idx_j, int* __restrict__ counts) {
    int p = blockIdx.x * 256 + threadIdx.x;
    if (p < N_PAIR) atomicAdd(&counts[idx_j[p]], 1);
}

// ---------------- exclusive scan of 8192 counts (1 block) ----------------
__global__ __launch_bounds__(1024) void k_scan(const int* __restrict__ counts,
                                               int* __restrict__ offsets) {
    __shared__ int ts[1024];
    int tid = threadIdx.x;
    int base = tid * 8;
    int v[8]; int tot = 0;
    #pragma unroll
    for (int q = 0; q < 8; ++q) { v[q] = counts[base + q]; tot += v[q]; }
    ts[tid] = tot; __syncthreads();
    for (int off = 1; off < 1024; off <<= 1) {
        int t2 = (tid >= off) ? ts[tid - off] : 0;
        __syncthreads();
        ts[tid] += t2;
        __syncthreads();
    }
    int excl = ts[tid] - tot;
    #pragma unroll
    for (int q = 0; q < 8; ++q) { offsets[base + q] = excl; excl += v[q]; }
    if (tid == 1023) offsets[N_ATOMS] = ts[1023];
}

// ---------------- placement: sorted pair ids per j-bucket ----------------
__global__ void k_place(const int* __restrict__ idx_j, const int* __restrict__ offsets,
                        int* __restrict__ cnt2, int* __restrict__ sorted) {
    int p = blockIdx.x * 256 + threadIdx.x;
    if (p < N_PAIR) {
        int j = idx_j[p];
        int pos = offsets[j] + atomicAdd(&cnt2[j], 1);
        sorted[pos] = p;
    }
}

// ---------------- K_wc: combined weights ----------------
// Wc[side][dh][k][j] = sum_c W2[k, col(d,h,side,c)] * a[dh, side*16+c] * W(side)[d,h,c,j]
// bc[side][dh][j]    = sum_c b2[col(d,h,side,c)]    * a[dh, side*16+c] * W(side)[d,h,c,j]
__global__ __launch_bounds__(256) void k_wc(
    const float* __restrict__ WQ, const float* __restrict__ WK,
    const float* __restrict__ avec, const float* __restrict__ W2,
    const float* __restrict__ b2,
    float* __restrict__ Wc, float* __restrict__ bc)
{
    int bx = blockIdx.x;             // 0..47
    int side = bx / NDH, dh = bx % NDH;
    int d = dh >> 3, h = dh & 7;
    int colbase = d * 256 + h * 32 + side * 16;
    const float* W = (side == 0) ? WQ : WK;
    __shared__ float w2s[64][16];
    __shared__ float ws[16][16];     // W[d][h][c][j]
    __shared__ float as[16];
    __shared__ float b2s[16];
    int tid = threadIdx.x;
    for (int e = tid; e < 64 * 16; e += 256)
        w2s[e >> 4][e & 15] = W2[(e >> 4) * FILT_OUT + colbase + (e & 15)];
    if (tid < 256) {
        if (tid < 16 * 16) ws[tid >> 4][tid & 15] = W[((d * 8 + h) * 16) * 16 + tid];
        if (tid < 16) { as[tid] = avec[dh * 32 + side * 16 + tid]; b2s[tid] = b2[colbase + tid]; }
    }
    __syncthreads();
    for (int o = tid; o < 64 * 16; o += 256) {
        int k = o >> 4, j = o & 15;
        float s = 0.f;
        #pragma unroll
        for (int c = 0; c < 16; ++c) s += w2s[k][c] * as[c] * ws[c][j];
        Wc[((size_t)bx * 64 + k) * 16 + j] = s;
    }
    if (tid < 16) {
        float s = 0.f;
        #pragma unroll
        for (int c = 0; c < 16; ++c) s += b2s[c] * as[c] * ws[c][tid];
        bc[bx * 16 + tid] = s;
    }
}

// ---------------- K_gfused: x -> Gq/Gk/bq/bk directly ----------------
__global__ __launch_bounds__(256) void k_gfused(
    const float* __restrict__ x, const float* __restrict__ Wc,
    const float* __restrict__ bc,
    __hip_bfloat16* __restrict__ Gq, __hip_bfloat16* __restrict__ Gk,
    float* __restrict__ bq, float* __restrict__ bk)
{
    int bx = blockIdx.x;             // 128 blocks of 64 atoms
    int by = blockIdx.y;             // 0..47: side, dh
    int side = by / NDH, dh = by % NDH;
    int h = dh & 7;
    int n0 = bx * 64;
    __shared__ float xh[64][17];     // padded: conflict-free per-at reads
    __shared__ float bcs[16];
    int tid = threadIdx.x;
    for (int e = tid; e < 64 * 16; e += 256)
        xh[e >> 4][e & 15] = x[(size_t)(n0 + (e >> 4)) * F + h * 16 + (e & 15)];
    if (tid < 16) bcs[tid] = bc[by * 16 + tid];
    int k = tid & 63, wv = tid >> 6;
    float wcr[16];
    const float* wp = Wc + ((size_t)by * 64 + k) * 16;
    #pragma unroll
    for (int j = 0; j < 16; ++j) wcr[j] = wp[j];
    __syncthreads();
    __hip_bfloat16* G = (side == 0) ? Gq : Gk;
    #pragma unroll 4
    for (int it = 0; it < 16; ++it) {
        int at = wv * 16 + it;
        float acc = 0.f;
        #pragma unroll
        for (int j = 0; j < 16; ++j) acc += wcr[j] * xh[at][j];  // broadcast reads
        G[(size_t)(n0 + at) * 1536 + dh * 64 + k] = __float2bfloat16(acc);
    }
    if (tid < 64) {
        float* B = (side == 0) ? bq : bk;
        float s = 0.f;
        #pragma unroll
        for (int j = 0; j < 16; ++j) s += bcs[j] * xh[tid][j];
        B[(n0 + tid) * NDH + dh] = s;
    }
}

// ---------------- K2a: h1[p,64] = silu(rbf @ W1 + b1), bf16 ----------------
__global__ __launch_bounds__(256) void k_h1(
    const float* __restrict__ rbf, const float* __restrict__ W1,
    const float* __restrict__ b1, unsigned short* __restrict__ h1)
{
    __shared__ float w1s[K_RBF][H_FILT]; // 8 KB
    __shared__ float b1s[H_FILT];
    __shared__ float rbfs[64][33];       // padded
    int tid = threadIdx.x;
    int p0 = blockIdx.x * 64;
    for (int e = tid; e < K_RBF * H_FILT; e += 256) w1s[e >> 6][e & 63] = W1[e];
    if (tid < H_FILT) b1s[tid] = b1[tid];
    for (int e = tid; e < 64 * K_RBF; e += 256)
        rbfs[e >> 5][e & 31] = rbf[(size_t)p0 * K_RBF + e];
    __syncthreads();
    int pp = tid >> 2;
    int kbase = (tid & 3) * 16;
    float acc[16];
    #pragma unroll
    for (int q = 0; q < 16; ++q) acc[q] = b1s[kbase + q];
    for (int c = 0; c < K_RBF; ++c) {
        float r = rbfs[pp][c];
        #pragma unroll
        for (int q = 0; q < 16; ++q) acc[q] += r * w1s[c][kbase + q];
    }
    u16x8 o0, o1;
    #pragma unroll
    for (int q = 0; q < 8; ++q) {
        float s0 = acc[q];     o0[q] = f2bfbits(s0 / (1.f + __expf(-s0)));
        float s1 = acc[q + 8]; o1[q] = f2bfbits(s1 / (1.f + __expf(-s1)));
    }
    unsigned short* hp = h1 + (size_t)(p0 + pp) * 64 + kbase;
    *reinterpret_cast<u16x8*>(hp) = o0;
    *reinterpret_cast<u16x8*>(hp + 8) = o1;
}

// ---------------- K2b: Q-side alpha (pair-major, idx_i sorted => cached Gq) ----------------
__global__ __launch_bounds__(256) void k_alpha_q(
    const int* __restrict__ idx_i,
    const unsigned short* __restrict__ h1,
    const __hip_bfloat16* __restrict__ Gq, const float* __restrict__ bq,
    float* __restrict__ alpha)
{
    __shared__ unsigned short h1s[8][64];
    int tid = threadIdx.x;
    int p0 = blockIdx.x * 8;
    if (tid < 64) {
        int pp = tid >> 3, seg = tid & 7;
        *reinterpret_cast<u16x8*>(&h1s[pp][seg * 8]) =
            *reinterpret_cast<const u16x8*>(h1 + (size_t)(p0 + pp) * 64 + seg * 8);
    }
    __syncthreads();
    int pp = tid >> 5, lane = tid & 31;
    if (lane < NDH) {
        int p = p0 + pp;
        int i = idx_i[p];
        float acc = bq[i * NDH + lane];
        const __hip_bfloat16* gq = Gq + (size_t)i * 1536 + lane * 64;
        #pragma unroll
        for (int v = 0; v < 8; ++v) {
            u16x8 qv = *reinterpret_cast<const u16x8*>(gq + v * 8);
            u16x8 hv = *reinterpret_cast<const u16x8*>(&h1s[pp][v * 8]);
            #pragma unroll
            for (int e = 0; e < 8; ++e) acc += bf2f(qv[e]) * bf2f(hv[e]);
        }
        alpha[(size_t)p * NDH + lane] = acc;
    }
}

// ---------------- K2c: K-side alpha (j-bucketed: Gk streamed once) ----------------
__global__ __launch_bounds__(256) void k_alpha_k(
    const int* __restrict__ sorted, const int* __restrict__ offsets,
    const unsigned short* __restrict__ h1,
    const __hip_bfloat16* __restrict__ Gk, const float* __restrict__ bk,
    const float* __restrict__ phi, const float* __restrict__ mask,
    float* __restrict__ alpha)
{
    __shared__ unsigned short h1s[8][64];
    int j = blockIdx.x;
    int s = offsets[j], e = offsets[j + 1];
    if (s == e) return;
    int tid = threadIdx.x;
    int pp = tid >> 5, lane = tid & 31;
    float bkj = (lane < NDH) ? bk[j * NDH + lane] : 0.f;
    const __hip_bfloat16* gk = Gk + (size_t)j * 1536 + lane * 64;
    for (int c0 = s; c0 < e; c0 += 8) {
        int nb = min(8, e - c0);
        __syncthreads();
        if (tid < 64) {
            int sp = tid >> 3, seg = tid & 7;
            if (sp < nb) {
                int pid = sorted[c0 + sp];
                *reinterpret_cast<u16x8*>(&h1s[sp][seg * 8]) =
                    *reinterpret_cast<const u16x8*>(h1 + (size_t)pid * 64 + seg * 8);
            }
        }
        __syncthreads();
        if (lane < NDH && pp < nb) {
            int p = sorted[c0 + pp];
            float acc = 0.f;
            #pragma unroll
            for (int v = 0; v < 8; ++v) {
                u16x8 kv = *reinterpret_cast<const u16x8*>(gk + v * 8);
                u16x8 hv = *reinterpret_cast<const u16x8*>(&h1s[pp][v * 8]);
                #pragma unroll
                for (int ee = 0; ee < 8; ++ee) acc += bf2f(kv[ee]) * bf2f(hv[ee]);
            }
            size_t ai = (size_t)p * NDH + lane;
            float aprev = alpha[ai];
            alpha[ai] = (aprev + acc + bkj) * phi[p] * mask[p] * 0.25f;
        }
    }
}

// ---------------- K3: per-atom segment aggregation ----------------
__global__ __launch_bounds__(128) void k_aggr(
    const float* __restrict__ x, const float* __restrict__ sph,
    const float* __restrict__ mask, const int* __restrict__ idx_j,
    const float* __restrict__ alpha, const int* __restrict__ row_start,
    float* __restrict__ out)
{
    int i = blockIdx.x;
    int tid = threadIdx.x; // f = tid, 128 threads
    int h = tid >> 4;
    float acc[M_TOT];
    #pragma unroll
    for (int m = 0; m < M_TOT; ++m) acc[m] = 0.f;
    int pstart = row_start[i], pend = row_start[i + 1];
    __shared__ float al[8][NDH];
    __shared__ float sl[8][M_TOT];
    __shared__ float xml[8];
    __shared__ int   jl[8];
    for (int pc = pstart; pc < pend; pc += 8) {
        int nb = min(8, pend - pc);
        __syncthreads();
        for (int e = tid; e < nb * NDH; e += 128)
            al[e / NDH][e % NDH] = alpha[(size_t)(pc + e / NDH) * NDH + e % NDH];
        for (int e = tid; e < nb * M_TOT; e += 128)
            sl[e / M_TOT][e % M_TOT] = sph[(size_t)(pc + e / M_TOT) * M_TOT + e % M_TOT];
        if (tid < nb) { xml[tid] = mask[pc + tid]; jl[tid] = idx_j[pc + tid]; }
        __syncthreads();
        for (int q = 0; q < nb; ++q) {
            int j = jl[q];
            float xv = x[(size_t)j * F + tid] * xml[q];
            float c0 = al[q][0 + h], c1 = al[q][8 + h], c2 = al[q][16 + h];
            #pragma unroll
            for (int m = 0; m < 3; ++m)  acc[m] += c0 * sl[q][m] * xv;
            #pragma unroll
            for (int m = 3; m < 8; ++m)  acc[m] += c1 * sl[q][m] * xv;
            #pragma unroll
            for (int m = 8; m < 15; ++m) acc[m] += c2 * sl[q][m] * xv;
        }
    }
    size_t ob = (size_t)i * (M_TOT * F) + tid;
    #pragma unroll
    for (int m = 0; m < M_TOT; ++m) out[ob + m * F] = acc[m];
}

extern "C" void kernel_launch(void* const* d_in, const int* in_sizes, int n_in,
                              void* d_out, int out_size, void* d_ws, size_t ws_size,
                              hipStream_t stream) {
    const float* x     = (const float*)d_in[0];
    const float* rbf   = (const float*)d_in[1];
    const float* sph   = (const float*)d_in[2];
    const float* phi   = (const float*)d_in[3];
    const int*   idx_i = (const int*)d_in[4];
    const int*   idx_j = (const int*)d_in[5];
    const float* mask  = (const float*)d_in[6];
    const float* WQ    = (const float*)d_in[7];
    const float* WK    = (const float*)d_in[8];
    const float* av    = (const float*)d_in[9];
    const float* W1    = (const float*)d_in[10];
    const float* b1    = (const float*)d_in[11];
    const float* W2    = (const float*)d_in[12];
    const float* b2    = (const float*)d_in[13];
    float* out = (float*)d_out;
    char* ws = (char*)d_ws;

    // ws layout (bytes):
    // Gq  bf16 [0,        25165824)
    // Gk  bf16 [25165824, 50331648)
    // bq  f32  [50331648, 51118080)
    // bk  f32  [51118080, 51904512)
    // row_start [51904512, 51937536)
    // counts    [51937536, 51970304)
    // offsets   [51970304, 52003840)   (8193 ints)
    // cnt2      [52003840, 52036608)
    // sorted    [52036608, 52560896)
    // h1  bf16  [52560896, 69338112)
    // alpha f32 [69338112, 81921024)   -- Wc/bc alias its head (dead before alpha_q)
    __hip_bfloat16* Gq = (__hip_bfloat16*)(ws + 0);
    __hip_bfloat16* Gk = (__hip_bfloat16*)(ws + 25165824);
    float* bq = (float*)(ws + 50331648);
    float* bk = (float*)(ws + 51118080);
    int* row_start = (int*)(ws + 51904512);
    int* counts    = (int*)(ws + 51937536);
    int* offsets   = (int*)(ws + 51970304);
    int* cnt2      = (int*)(ws + 52003840);
    int* sorted    = (int*)(ws + 52036608);
    unsigned short* h1 = (unsigned short*)(ws + 52560896);
    float* alphaBuf = (float*)(ws + 69338112);
    float* Wc = (float*)(ws + 69338112);           // 196608 B, dead before alpha_q
    float* bc = (float*)(ws + 69338112 + 196608);  // 6144 B

    k_zero<<<(N_ATOMS + 255) / 256, 256, 0, stream>>>(counts, cnt2);
    k_seg<<<(N_PAIR + 255) / 256, 256, 0, stream>>>(idx_i, row_start);
    k_hist<<<(N_PAIR + 255) / 256, 256, 0, stream>>>(idx_j, counts);
    k_scan<<<1, 1024, 0, stream>>>(counts, offsets);
    k_place<<<(N_PAIR + 255) / 256, 256, 0, stream>>>(idx_j, offsets, cnt2, sorted);
    k_wc<<<48, 256, 0, stream>>>(WQ, WK, av, W1 /*unused*/ == W1 ? W2 : W2, b2, Wc, bc);
    k_gfused<<<dim3(N_ATOMS / 64, 48), 256, 0, stream>>>(x, Wc, bc, Gq, Gk, bq, bk);
    k_h1<<<N_PAIR / 64, 256, 0, stream>>>(rbf, W1, b1, h1);
    k_alpha_q<<<N_PAIR / 8, 256, 0, stream>>>(idx_i, h1, Gq, bq, alphaBuf);
    k_alpha_k<<<N_ATOMS, 256, 0, stream>>>(sorted, offsets, h1, Gk, bk, phi, mask, alphaBuf);
    k_aggr<<<N_ATOMS, 128, 0, stream>>>(x, sph, mask, idx_j, alphaBuf, row_start, out);
}

// Round 4
// 222.830 us; speedup vs baseline: 1.5280x; 1.0737x over previous
//
#include <hip/hip_runtime.h>
#include <hip/hip_bf16.h>

#define N_ATOMS 8192
#define N_PAIR  131072
#define F       128
#define N_HEAD  8
#define FH      16
#define N_DEG   3
#define M_TOT   15
#define K_RBF   32
#define H_FILT  64
#define FILT_OUT 768
#define NDH     24   // N_DEG * N_HEAD

typedef __attribute__((ext_vector_type(8))) unsigned short u16x8;

__device__ __forceinline__ float bf2f(unsigned short u) {
    return __uint_as_float(((unsigned)u) << 16);
}
__device__ __forceinline__ unsigned short f2bfbits(float f) {
    __hip_bfloat16 b = __float2bfloat16(f);
    return *reinterpret_cast<unsigned short*>(&b);
}

// ---------------- K0: segment starts (idx_i is sorted) ----------------
__global__ void k_seg(const int* __restrict__ idx_i, int* __restrict__ row_start) {
    int p = blockIdx.x * 256 + threadIdx.x;
    if (p >= N_PAIR) return;
    int ii = idx_i[p];
    int prev = (p == 0) ? -1 : idx_i[p - 1];
    for (int a = prev + 1; a <= ii; ++a) row_start[a] = p;
    if (p == N_PAIR - 1) {
        for (int a = ii + 1; a <= N_ATOMS; ++a) row_start[a] = N_PAIR;
    }
}

// ---------------- zero counters (graph-replay safe) ----------------
__global__ void k_zero(int* __restrict__ counts, int* __restrict__ cnt2) {
    int t = blockIdx.x * 256 + threadIdx.x;
    if (t < N_ATOMS) { counts[t] = 0; cnt2[t] = 0; }
}

// ---------------- histogram of idx_j ----------------
__global__ void k_hist(const int* __restrict__ idx_j, int* __restrict__ counts) {
    int p = blockIdx.x * 256 + threadIdx.x;
    if (p < N_PAIR) atomicAdd(&counts[idx_j[p]], 1);
}

// ---------------- exclusive scan of 8192 counts (1 block) ----------------
__global__ __launch_bounds__(1024) void k_scan(const int* __restrict__ counts,
                                               int* __restrict__ offsets) {
    __shared__ int ts[1024];
    int tid = threadIdx.x;
    int base = tid * 8;
    int v[8]; int tot = 0;
    #pragma unroll
    for (int q = 0; q < 8; ++q) { v[q] = counts[base + q]; tot += v[q]; }
    ts[tid] = tot; __syncthreads();
    for (int off = 1; off < 1024; off <<= 1) {
        int t2 = (tid >= off) ? ts[tid - off] : 0;
        __syncthreads();
        ts[tid] += t2;
        __syncthreads();
    }
    int excl = ts[tid] - tot;
    #pragma unroll
    for (int q = 0; q < 8; ++q) { offsets[base + q] = excl; excl += v[q]; }
    if (tid == 1023) offsets[N_ATOMS] = ts[1023];
}

// ---------------- placement: sorted pair ids per j-bucket ----------------
__global__ void k_place(const int* __restrict__ idx_j, const int* __restrict__ offsets,
                        int* __restrict__ cnt2, int* __restrict__ sorted) {
    int p = blockIdx.x * 256 + threadIdx.x;
    if (p < N_PAIR) {
        int j = idx_j[p];
        int pos = offsets[j] + atomicAdd(&cnt2[j], 1);
        sorted[pos] = p;
    }
}

// ---------------- K_wc: combined weights ----------------
__global__ __launch_bounds__(256) void k_wc(
    const float* __restrict__ WQ, const float* __restrict__ WK,
    const float* __restrict__ avec, const float* __restrict__ W2,
    const float* __restrict__ b2,
    float* __restrict__ Wc, float* __restrict__ bc)
{
    int bx = blockIdx.x;             // 0..47
    int side = bx / NDH, dh = bx % NDH;
    int d = dh >> 3, h = dh & 7;
    int colbase = d * 256 + h * 32 + side * 16;
    const float* W = (side == 0) ? WQ : WK;
    __shared__ float w2s[64][16];
    __shared__ float ws[16][16];     // W[d][h][c][j]
    __shared__ float as[16];
    __shared__ float b2s[16];
    int tid = threadIdx.x;
    for (int e = tid; e < 64 * 16; e += 256)
        w2s[e >> 4][e & 15] = W2[(e >> 4) * FILT_OUT + colbase + (e & 15)];
    if (tid < 16 * 16) ws[tid >> 4][tid & 15] = W[((d * 8 + h) * 16) * 16 + tid];
    if (tid < 16) { as[tid] = avec[dh * 32 + side * 16 + tid]; b2s[tid] = b2[colbase + tid]; }
    __syncthreads();
    for (int o = tid; o < 64 * 16; o += 256) {
        int k = o >> 4, j = o & 15;
        float s = 0.f;
        #pragma unroll
        for (int c = 0; c < 16; ++c) s += w2s[k][c] * as[c] * ws[c][j];
        Wc[((size_t)bx * 64 + k) * 16 + j] = s;
    }
    if (tid < 16) {
        float s = 0.f;
        #pragma unroll
        for (int c = 0; c < 16; ++c) s += b2s[c] * as[c] * ws[c][tid];
        bc[bx * 16 + tid] = s;
    }
}

// ---------------- K_gfused: x -> Gq/Gk/bq/bk directly ----------------
__global__ __launch_bounds__(256) void k_gfused(
    const float* __restrict__ x, const float* __restrict__ Wc,
    const float* __restrict__ bc,
    __hip_bfloat16* __restrict__ Gq, __hip_bfloat16* __restrict__ Gk,
    float* __restrict__ bq, float* __restrict__ bk)
{
    int bx = blockIdx.x;             // 128 blocks of 64 atoms
    int by = blockIdx.y;             // 0..47: side, dh
    int side = by / NDH, dh = by % NDH;
    int h = dh & 7;
    int n0 = bx * 64;
    __shared__ float xh[64][17];     // padded: conflict-free per-at reads
    __shared__ float bcs[16];
    int tid = threadIdx.x;
    for (int e = tid; e < 64 * 16; e += 256)
        xh[e >> 4][e & 15] = x[(size_t)(n0 + (e >> 4)) * F + h * 16 + (e & 15)];
    if (tid < 16) bcs[tid] = bc[by * 16 + tid];
    int k = tid & 63, wv = tid >> 6;
    float wcr[16];
    const float* wp = Wc + ((size_t)by * 64 + k) * 16;
    #pragma unroll
    for (int j = 0; j < 16; ++j) wcr[j] = wp[j];
    __syncthreads();
    __hip_bfloat16* G = (side == 0) ? Gq : Gk;
    #pragma unroll 4
    for (int it = 0; it < 16; ++it) {
        int at = wv * 16 + it;
        float acc = 0.f;
        #pragma unroll
        for (int j = 0; j < 16; ++j) acc += wcr[j] * xh[at][j];  // broadcast reads
        G[(size_t)(n0 + at) * 1536 + dh * 64 + k] = __float2bfloat16(acc);
    }
    if (tid < 64) {
        float* B = (side == 0) ? bq : bk;
        float s = 0.f;
        #pragma unroll
        for (int j = 0; j < 16; ++j) s += bcs[j] * xh[tid][j];
        B[(n0 + tid) * NDH + dh] = s;
    }
}

// ---------------- K2a: h1[p,64] = silu(rbf @ W1 + b1), bf16 ----------------
__global__ __launch_bounds__(256) void k_h1(
    const float* __restrict__ rbf, const float* __restrict__ W1,
    const float* __restrict__ b1, unsigned short* __restrict__ h1)
{
    __shared__ float w1s[K_RBF][H_FILT]; // 8 KB
    __shared__ float b1s[H_FILT];
    __shared__ float rbfs[64][33];       // padded
    int tid = threadIdx.x;
    int p0 = blockIdx.x * 64;
    for (int e = tid; e < K_RBF * H_FILT; e += 256) w1s[e >> 6][e & 63] = W1[e];
    if (tid < H_FILT) b1s[tid] = b1[tid];
    for (int e = tid; e < 64 * K_RBF; e += 256)
        rbfs[e >> 5][e & 31] = rbf[(size_t)p0 * K_RBF + e];
    __syncthreads();
    int pp = tid >> 2;
    int kbase = (tid & 3) * 16;
    float acc[16];
    #pragma unroll
    for (int q = 0; q < 16; ++q) acc[q] = b1s[kbase + q];
    for (int c = 0; c < K_RBF; ++c) {
        float r = rbfs[pp][c];
        #pragma unroll
        for (int q = 0; q < 16; ++q) acc[q] += r * w1s[c][kbase + q];
    }
    u16x8 o0, o1;
    #pragma unroll
    for (int q = 0; q < 8; ++q) {
        float s0 = acc[q];     o0[q] = f2bfbits(s0 / (1.f + __expf(-s0)));
        float s1 = acc[q + 8]; o1[q] = f2bfbits(s1 / (1.f + __expf(-s1)));
    }
    unsigned short* hp = h1 + (size_t)(p0 + pp) * 64 + kbase;
    *reinterpret_cast<u16x8*>(hp) = o0;
    *reinterpret_cast<u16x8*>(hp + 8) = o1;
}

// ---------------- K2b: Q-side alpha, flat tasks (pairs in natural i-sorted order) ----------------
__global__ __launch_bounds__(256) void k_alpha_q2(
    const int* __restrict__ idx_i,
    const unsigned short* __restrict__ h1,
    const __hip_bfloat16* __restrict__ Gq, const float* __restrict__ bq,
    float* __restrict__ alpha)
{
    __shared__ unsigned short h1s[128][64]; // 16 KB
    __shared__ int is[128];
    int tid = threadIdx.x;
    int p0 = blockIdx.x * 128;
    for (int e = tid; e < 128 * 8; e += 256) {
        int slot = e >> 3, seg = e & 7;
        *reinterpret_cast<u16x8*>(&h1s[slot][seg * 8]) =
            *reinterpret_cast<const u16x8*>(h1 + (size_t)(p0 + slot) * 64 + seg * 8);
    }
    if (tid < 128) is[tid] = idx_i[p0 + tid];
    __syncthreads();
    #pragma unroll
    for (int t = 0; t < 12; ++t) {
        int task = t * 256 + tid;        // 0..3071
        int slot = task / 24;
        int dh = task - slot * 24;
        int i = is[slot];
        float acc = bq[i * NDH + dh];
        const __hip_bfloat16* gq = Gq + (size_t)i * 1536 + dh * 64;
        const unsigned short* hp = &h1s[slot][0];
        #pragma unroll
        for (int v = 0; v < 8; ++v) {
            u16x8 qv = *reinterpret_cast<const u16x8*>(gq + v * 8);
            u16x8 hv = *reinterpret_cast<const u16x8*>(hp + v * 8);
            #pragma unroll
            for (int e = 0; e < 8; ++e) acc += bf2f(qv[e]) * bf2f(hv[e]);
        }
        alpha[(size_t)(p0 + slot) * NDH + dh] = acc;
    }
}

// ---------------- K2c: K-side alpha, flat tasks over sorted[] (j-sorted order) ----------------
__global__ __launch_bounds__(256) void k_alpha_k2(
    const int* __restrict__ sorted, const int* __restrict__ idx_j,
    const unsigned short* __restrict__ h1,
    const __hip_bfloat16* __restrict__ Gk, const float* __restrict__ bk,
    const float* __restrict__ phi, const float* __restrict__ mask,
    float* __restrict__ alpha)
{
    __shared__ unsigned short h1s[128][64]; // 16 KB
    __shared__ int ps[128];
    __shared__ int js[128];
    __shared__ float pm[128];
    int tid = threadIdx.x;
    int c0 = blockIdx.x * 128;
    if (tid < 128) {
        int pid = sorted[c0 + tid];
        ps[tid] = pid;
        js[tid] = idx_j[pid];
        pm[tid] = phi[pid] * mask[pid] * 0.25f;
    }
    __syncthreads();
    for (int e = tid; e < 128 * 8; e += 256) {
        int slot = e >> 3, seg = e & 7;
        *reinterpret_cast<u16x8*>(&h1s[slot][seg * 8]) =
            *reinterpret_cast<const u16x8*>(h1 + (size_t)ps[slot] * 64 + seg * 8);
    }
    __syncthreads();
    #pragma unroll
    for (int t = 0; t < 12; ++t) {
        int task = t * 256 + tid;        // 0..3071
        int slot = task / 24;
        int dh = task - slot * 24;
        int j = js[slot];
        float acc = bk[j * NDH + dh];
        const __hip_bfloat16* gk = Gk + (size_t)j * 1536 + dh * 64;
        const unsigned short* hp = &h1s[slot][0];
        #pragma unroll
        for (int v = 0; v < 8; ++v) {
            u16x8 kv = *reinterpret_cast<const u16x8*>(gk + v * 8);
            u16x8 hv = *reinterpret_cast<const u16x8*>(hp + v * 8);
            #pragma unroll
            for (int e = 0; e < 8; ++e) acc += bf2f(kv[e]) * bf2f(hv[e]);
        }
        size_t ai = (size_t)ps[slot] * NDH + dh;
        alpha[ai] = (alpha[ai] + acc) * pm[slot];
    }
}

// ---------------- K3: per-atom segment aggregation ----------------
__global__ __launch_bounds__(128) void k_aggr(
    const float* __restrict__ x, const float* __restrict__ sph,
    const float* __restrict__ mask, const int* __restrict__ idx_j,
    const float* __restrict__ alpha, const int* __restrict__ row_start,
    float* __restrict__ out)
{
    int i = blockIdx.x;
    int tid = threadIdx.x; // f = tid, 128 threads
    int h = tid >> 4;
    float acc[M_TOT];
    #pragma unroll
    for (int m = 0; m < M_TOT; ++m) acc[m] = 0.f;
    int pstart = row_start[i], pend = row_start[i + 1];
    __shared__ float al[8][NDH];
    __shared__ float sl[8][M_TOT];
    __shared__ float xml[8];
    __shared__ int   jl[8];
    for (int pc = pstart; pc < pend; pc += 8) {
        int nb = min(8, pend - pc);
        __syncthreads();
        for (int e = tid; e < nb * NDH; e += 128)
            al[e / NDH][e % NDH] = alpha[(size_t)(pc + e / NDH) * NDH + e % NDH];
        for (int e = tid; e < nb * M_TOT; e += 128)
            sl[e / M_TOT][e % M_TOT] = sph[(size_t)(pc + e / M_TOT) * M_TOT + e % M_TOT];
        if (tid < nb) { xml[tid] = mask[pc + tid]; jl[tid] = idx_j[pc + tid]; }
        __syncthreads();
        for (int q = 0; q < nb; ++q) {
            int j = jl[q];
            float xv = x[(size_t)j * F + tid] * xml[q];
            float c0 = al[q][0 + h], c1 = al[q][8 + h], c2 = al[q][16 + h];
            #pragma unroll
            for (int m = 0; m < 3; ++m)  acc[m] += c0 * sl[q][m] * xv;
            #pragma unroll
            for (int m = 3; m < 8; ++m)  acc[m] += c1 * sl[q][m] * xv;
            #pragma unroll
            for (int m = 8; m < 15; ++m) acc[m] += c2 * sl[q][m] * xv;
        }
    }
    size_t ob = (size_t)i * (M_TOT * F) + tid;
    #pragma unroll
    for (int m = 0; m < M_TOT; ++m) out[ob + m * F] = acc[m];
}

extern "C" void kernel_launch(void* const* d_in, const int* in_sizes, int n_in,
                              void* d_out, int out_size, void* d_ws, size_t ws_size,
                              hipStream_t stream) {
    const float* x     = (const float*)d_in[0];
    const float* rbf   = (const float*)d_in[1];
    const float* sph   = (const float*)d_in[2];
    const float* phi   = (const float*)d_in[3];
    const int*   idx_i = (const int*)d_in[4];
    const int*   idx_j = (const int*)d_in[5];
    const float* mask  = (const float*)d_in[6];
    const float* WQ    = (const float*)d_in[7];
    const float* WK    = (const float*)d_in[8];
    const float* av    = (const float*)d_in[9];
    const float* W1    = (const float*)d_in[10];
    const float* b1    = (const float*)d_in[11];
    const float* W2    = (const float*)d_in[12];
    const float* b2    = (const float*)d_in[13];
    float* out = (float*)d_out;
    char* ws = (char*)d_ws;

    // ws layout (bytes):
    // Gq  bf16 [0,        25165824)
    // Gk  bf16 [25165824, 50331648)
    // bq  f32  [50331648, 51118080)
    // bk  f32  [51118080, 51904512)
    // row_start [51904512, 51937536)
    // counts    [51937536, 51970304)
    // offsets   [51970304, 52003840)   (8193 ints)
    // cnt2      [52003840, 52036608)
    // sorted    [52036608, 52560896)
    // h1  bf16  [52560896, 69338112)
    // alpha f32 [69338112, 81921024)   -- Wc/bc alias its head (dead before alpha_q2)
    __hip_bfloat16* Gq = (__hip_bfloat16*)(ws + 0);
    __hip_bfloat16* Gk = (__hip_bfloat16*)(ws + 25165824);
    float* bq = (float*)(ws + 50331648);
    float* bk = (float*)(ws + 51118080);
    int* row_start = (int*)(ws + 51904512);
    int* counts    = (int*)(ws + 51937536);
    int* offsets   = (int*)(ws + 51970304);
    int* cnt2      = (int*)(ws + 52003840);
    int* sorted    = (int*)(ws + 52036608);
    unsigned short* h1 = (unsigned short*)(ws + 52560896);
    float* alphaBuf = (float*)(ws + 69338112);
    float* Wc = (float*)(ws + 69338112);           // 196608 B, dead before alpha_q2
    float* bc = (float*)(ws + 69338112 + 196608);  // 6144 B

    k_zero<<<(N_ATOMS + 255) / 256, 256, 0, stream>>>(counts, cnt2);
    k_seg<<<(N_PAIR + 255) / 256, 256, 0, stream>>>(idx_i, row_start);
    k_hist<<<(N_PAIR + 255) / 256, 256, 0, stream>>>(idx_j, counts);
    k_scan<<<1, 1024, 0, stream>>>(counts, offsets);
    k_place<<<(N_PAIR + 255) / 256, 256, 0, stream>>>(idx_j, offsets, cnt2, sorted);
    k_wc<<<48, 256, 0, stream>>>(WQ, WK, av, W2, b2, Wc, bc);
    k_gfused<<<dim3(N_ATOMS / 64, 48), 256, 0, stream>>>(x, Wc, bc, Gq, Gk, bq, bk);
    k_h1<<<N_PAIR / 64, 256, 0, stream>>>(rbf, W1, b1, h1);
    k_alpha_q2<<<N_PAIR / 128, 256, 0, stream>>>(idx_i, h1, Gq, bq, alphaBuf);
    k_alpha_k2<<<N_PAIR / 128, 256, 0, stream>>>(sorted, idx_j, h1, Gk, bk, phi, mask, alphaBuf);
    k_aggr<<<N_ATOMS, 128, 0, stream>>>(x, sph, mask, idx_j, alphaBuf, row_start, out);
}

// Round 5
// 222.441 us; speedup vs baseline: 1.5307x; 1.0018x over previous
//
#include <hip/hip_runtime.h>
#include <hip/hip_bf16.h>

#define N_ATOMS 8192
#define N_PAIR  131072
#define F       128
#define N_HEAD  8
#define FH      16
#define N_DEG   3
#define M_TOT   15
#define K_RBF   32
#define H_FILT  64
#define FILT_OUT 768
#define NDH     24   // N_DEG * N_HEAD

typedef __attribute__((ext_vector_type(8))) unsigned short u16x8;

__device__ __forceinline__ float bf2f(unsigned short u) {
    return __uint_as_float(((unsigned)u) << 16);
}
__device__ __forceinline__ unsigned short f2bfbits(float f) {
    __hip_bfloat16 b = __float2bfloat16(f);
    return *reinterpret_cast<unsigned short*>(&b);
}

// ---------------- K0: segment starts (idx_i is sorted) ----------------
__global__ void k_seg(const int* __restrict__ idx_i, int* __restrict__ row_start) {
    int p = blockIdx.x * 256 + threadIdx.x;
    if (p >= N_PAIR) return;
    int ii = idx_i[p];
    int prev = (p == 0) ? -1 : idx_i[p - 1];
    for (int a = prev + 1; a <= ii; ++a) row_start[a] = p;
    if (p == N_PAIR - 1) {
        for (int a = ii + 1; a <= N_ATOMS; ++a) row_start[a] = N_PAIR;
    }
}

// ---------------- zero counters (graph-replay safe) ----------------
__global__ void k_zero(int* __restrict__ counts, int* __restrict__ cnt2) {
    int t = blockIdx.x * 256 + threadIdx.x;
    if (t < N_ATOMS) { counts[t] = 0; cnt2[t] = 0; }
}

// ---------------- histogram of idx_j ----------------
__global__ void k_hist(const int* __restrict__ idx_j, int* __restrict__ counts) {
    int p = blockIdx.x * 256 + threadIdx.x;
    if (p < N_PAIR) atomicAdd(&counts[idx_j[p]], 1);
}

// ---------------- exclusive scan of 8192 counts (1 block) ----------------
__global__ __launch_bounds__(1024) void k_scan(const int* __restrict__ counts,
                                               int* __restrict__ offsets) {
    __shared__ int ts[1024];
    int tid = threadIdx.x;
    int base = tid * 8;
    int v[8]; int tot = 0;
    #pragma unroll
    for (int q = 0; q < 8; ++q) { v[q] = counts[base + q]; tot += v[q]; }
    ts[tid] = tot; __syncthreads();
    for (int off = 1; off < 1024; off <<= 1) {
        int t2 = (tid >= off) ? ts[tid - off] : 0;
        __syncthreads();
        ts[tid] += t2;
        __syncthreads();
    }
    int excl = ts[tid] - tot;
    #pragma unroll
    for (int q = 0; q < 8; ++q) { offsets[base + q] = excl; excl += v[q]; }
    if (tid == 1023) offsets[N_ATOMS] = ts[1023];
}

// ---------------- placement: sorted pair ids per j-bucket ----------------
__global__ void k_place(const int* __restrict__ idx_j, const int* __restrict__ offsets,
                        int* __restrict__ cnt2, int* __restrict__ sorted) {
    int p = blockIdx.x * 256 + threadIdx.x;
    if (p < N_PAIR) {
        int j = idx_j[p];
        int pos = offsets[j] + atomicAdd(&cnt2[j], 1);
        sorted[pos] = p;
    }
}

// ---------------- K_wc: combined weights ----------------
__global__ __launch_bounds__(256) void k_wc(
    const float* __restrict__ WQ, const float* __restrict__ WK,
    const float* __restrict__ avec, const float* __restrict__ W2,
    const float* __restrict__ b2,
    float* __restrict__ Wc, float* __restrict__ bc)
{
    int bx = blockIdx.x;             // 0..47
    int side = bx / NDH, dh = bx % NDH;
    int d = dh >> 3, h = dh & 7;
    int colbase = d * 256 + h * 32 + side * 16;
    const float* W = (side == 0) ? WQ : WK;
    __shared__ float w2s[64][16];
    __shared__ float ws[16][16];     // W[d][h][c][j]
    __shared__ float as[16];
    __shared__ float b2s[16];
    int tid = threadIdx.x;
    for (int e = tid; e < 64 * 16; e += 256)
        w2s[e >> 4][e & 15] = W2[(e >> 4) * FILT_OUT + colbase + (e & 15)];
    if (tid < 16 * 16) ws[tid >> 4][tid & 15] = W[((d * 8 + h) * 16) * 16 + tid];
    if (tid < 16) { as[tid] = avec[dh * 32 + side * 16 + tid]; b2s[tid] = b2[colbase + tid]; }
    __syncthreads();
    for (int o = tid; o < 64 * 16; o += 256) {
        int k = o >> 4, j = o & 15;
        float s = 0.f;
        #pragma unroll
        for (int c = 0; c < 16; ++c) s += w2s[k][c] * as[c] * ws[c][j];
        Wc[((size_t)bx * 64 + k) * 16 + j] = s;
    }
    if (tid < 16) {
        float s = 0.f;
        #pragma unroll
        for (int c = 0; c < 16; ++c) s += b2s[c] * as[c] * ws[c][tid];
        bc[bx * 16 + tid] = s;
    }
}

// ---------------- K_gfused: x -> Gq/Gk/bq/bk directly ----------------
__global__ __launch_bounds__(256) void k_gfused(
    const float* __restrict__ x, const float* __restrict__ Wc,
    const float* __restrict__ bc,
    __hip_bfloat16* __restrict__ Gq, __hip_bfloat16* __restrict__ Gk,
    float* __restrict__ bq, float* __restrict__ bk)
{
    int bx = blockIdx.x;             // 128 blocks of 64 atoms
    int by = blockIdx.y;             // 0..47: side, dh
    int side = by / NDH, dh = by % NDH;
    int h = dh & 7;
    int n0 = bx * 64;
    __shared__ float xh[64][17];     // padded: conflict-free per-at reads
    __shared__ float bcs[16];
    int tid = threadIdx.x;
    for (int e = tid; e < 64 * 16; e += 256)
        xh[e >> 4][e & 15] = x[(size_t)(n0 + (e >> 4)) * F + h * 16 + (e & 15)];
    if (tid < 16) bcs[tid] = bc[by * 16 + tid];
    int k = tid & 63, wv = tid >> 6;
    float wcr[16];
    const float* wp = Wc + ((size_t)by * 64 + k) * 16;
    #pragma unroll
    for (int j = 0; j < 16; ++j) wcr[j] = wp[j];
    __syncthreads();
    __hip_bfloat16* G = (side == 0) ? Gq : Gk;
    #pragma unroll 4
    for (int it = 0; it < 16; ++it) {
        int at = wv * 16 + it;
        float acc = 0.f;
        #pragma unroll
        for (int j = 0; j < 16; ++j) acc += wcr[j] * xh[at][j];  // broadcast reads
        G[(size_t)(n0 + at) * 1536 + dh * 64 + k] = __float2bfloat16(acc);
    }
    if (tid < 64) {
        float* B = (side == 0) ? bq : bk;
        float s = 0.f;
        #pragma unroll
        for (int j = 0; j < 16; ++j) s += bcs[j] * xh[tid][j];
        B[(n0 + tid) * NDH + dh] = s;
    }
}

// ---------------- K2a: h1[p,64] = silu(rbf @ W1 + b1), bf16 ----------------
__global__ __launch_bounds__(256) void k_h1(
    const float* __restrict__ rbf, const float* __restrict__ W1,
    const float* __restrict__ b1, unsigned short* __restrict__ h1)
{
    __shared__ float w1s[K_RBF][H_FILT]; // 8 KB
    __shared__ float b1s[H_FILT];
    __shared__ float rbfs[64][33];       // padded
    int tid = threadIdx.x;
    int p0 = blockIdx.x * 64;
    for (int e = tid; e < K_RBF * H_FILT; e += 256) w1s[e >> 6][e & 63] = W1[e];
    if (tid < H_FILT) b1s[tid] = b1[tid];
    for (int e = tid; e < 64 * K_RBF; e += 256)
        rbfs[e >> 5][e & 31] = rbf[(size_t)p0 * K_RBF + e];
    __syncthreads();
    int pp = tid >> 2;
    int kbase = (tid & 3) * 16;
    float acc[16];
    #pragma unroll
    for (int q = 0; q < 16; ++q) acc[q] = b1s[kbase + q];
    for (int c = 0; c < K_RBF; ++c) {
        float r = rbfs[pp][c];
        #pragma unroll
        for (int q = 0; q < 16; ++q) acc[q] += r * w1s[c][kbase + q];
    }
    u16x8 o0, o1;
    #pragma unroll
    for (int q = 0; q < 8; ++q) {
        float s0 = acc[q];     o0[q] = f2bfbits(s0 / (1.f + __expf(-s0)));
        float s1 = acc[q + 8]; o1[q] = f2bfbits(s1 / (1.f + __expf(-s1)));
    }
    unsigned short* hp = h1 + (size_t)(p0 + pp) * 64 + kbase;
    *reinterpret_cast<u16x8*>(hp) = o0;
    *reinterpret_cast<u16x8*>(hp + 8) = o1;
}

// ---------------- K2b: Q-side alpha, flat tasks, 64 slots/block, batched loads ----------------
__global__ __launch_bounds__(256) void k_alpha_q2(
    const int* __restrict__ idx_i,
    const unsigned short* __restrict__ h1,
    const __hip_bfloat16* __restrict__ Gq, const float* __restrict__ bq,
    float* __restrict__ alpha)
{
    __shared__ unsigned short h1s[64][64]; // 8 KB
    __shared__ int is[64];
    int tid = threadIdx.x;
    int p0 = blockIdx.x * 64;
    for (int e = tid; e < 64 * 8; e += 256) {
        int slot = e >> 3, seg = e & 7;
        *reinterpret_cast<u16x8*>(&h1s[slot][seg * 8]) =
            *reinterpret_cast<const u16x8*>(h1 + (size_t)(p0 + slot) * 64 + seg * 8);
    }
    if (tid < 64) is[tid] = idx_i[p0 + tid];
    __syncthreads();
    #pragma unroll 1
    for (int t = 0; t < 6; ++t) {
        int task = t * 256 + tid;        // 0..1535
        int slot = task / 24;
        int dh = task - slot * 24;
        int i = is[slot];
        const __hip_bfloat16* gq = Gq + (size_t)i * 1536 + dh * 64;
        // batch all 8 global loads (independent -> in flight together)
        u16x8 qv[8];
        #pragma unroll
        for (int v = 0; v < 8; ++v) qv[v] = *reinterpret_cast<const u16x8*>(gq + v * 8);
        float bqv = bq[i * NDH + dh];
        float a0 = 0.f, a1 = 0.f, a2 = 0.f, a3 = 0.f;
        #pragma unroll
        for (int v = 0; v < 8; ++v) {
            u16x8 hv = *reinterpret_cast<const u16x8*>(&h1s[slot][v * 8]);
            a0 += bf2f(qv[v][0]) * bf2f(hv[0]);
            a1 += bf2f(qv[v][1]) * bf2f(hv[1]);
            a2 += bf2f(qv[v][2]) * bf2f(hv[2]);
            a3 += bf2f(qv[v][3]) * bf2f(hv[3]);
            a0 += bf2f(qv[v][4]) * bf2f(hv[4]);
            a1 += bf2f(qv[v][5]) * bf2f(hv[5]);
            a2 += bf2f(qv[v][6]) * bf2f(hv[6]);
            a3 += bf2f(qv[v][7]) * bf2f(hv[7]);
        }
        alpha[(size_t)(p0 + slot) * NDH + dh] = bqv + (a0 + a1) + (a2 + a3);
    }
}

// ---------------- K2c: K-side alpha, flat tasks over sorted[], 64 slots/block ----------------
__global__ __launch_bounds__(256) void k_alpha_k2(
    const int* __restrict__ sorted, const int* __restrict__ idx_j,
    const unsigned short* __restrict__ h1,
    const __hip_bfloat16* __restrict__ Gk, const float* __restrict__ bk,
    const float* __restrict__ phi, const float* __restrict__ mask,
    float* __restrict__ alpha)
{
    __shared__ unsigned short h1s[64][64]; // 8 KB
    __shared__ int ps[64];
    __shared__ int js[64];
    __shared__ float pm[64];
    int tid = threadIdx.x;
    int c0 = blockIdx.x * 64;
    if (tid < 64) {
        int pid = sorted[c0 + tid];
        ps[tid] = pid;
        js[tid] = idx_j[pid];
        pm[tid] = phi[pid] * mask[pid] * 0.25f;
    }
    __syncthreads();
    for (int e = tid; e < 64 * 8; e += 256) {
        int slot = e >> 3, seg = e & 7;
        *reinterpret_cast<u16x8*>(&h1s[slot][seg * 8]) =
            *reinterpret_cast<const u16x8*>(h1 + (size_t)ps[slot] * 64 + seg * 8);
    }
    __syncthreads();
    #pragma unroll 1
    for (int t = 0; t < 6; ++t) {
        int task = t * 256 + tid;        // 0..1535
        int slot = task / 24;
        int dh = task - slot * 24;
        int j = js[slot];
        const __hip_bfloat16* gk = Gk + (size_t)j * 1536 + dh * 64;
        u16x8 kv[8];
        #pragma unroll
        for (int v = 0; v < 8; ++v) kv[v] = *reinterpret_cast<const u16x8*>(gk + v * 8);
        float bkv = bk[j * NDH + dh];
        size_t ai = (size_t)ps[slot] * NDH + dh;
        float aprev = alpha[ai];
        float a0 = 0.f, a1 = 0.f, a2 = 0.f, a3 = 0.f;
        #pragma unroll
        for (int v = 0; v < 8; ++v) {
            u16x8 hv = *reinterpret_cast<const u16x8*>(&h1s[slot][v * 8]);
            a0 += bf2f(kv[v][0]) * bf2f(hv[0]);
            a1 += bf2f(kv[v][1]) * bf2f(hv[1]);
            a2 += bf2f(kv[v][2]) * bf2f(hv[2]);
            a3 += bf2f(kv[v][3]) * bf2f(hv[3]);
            a0 += bf2f(kv[v][4]) * bf2f(hv[4]);
            a1 += bf2f(kv[v][5]) * bf2f(hv[5]);
            a2 += bf2f(kv[v][6]) * bf2f(hv[6]);
            a3 += bf2f(kv[v][7]) * bf2f(hv[7]);
        }
        alpha[ai] = (aprev + bkv + (a0 + a1) + (a2 + a3)) * pm[slot];
    }
}

// ---------------- K3: per-atom segment aggregation ----------------
__global__ __launch_bounds__(128) void k_aggr(
    const float* __restrict__ x, const float* __restrict__ sph,
    const float* __restrict__ mask, const int* __restrict__ idx_j,
    const float* __restrict__ alpha, const int* __restrict__ row_start,
    float* __restrict__ out)
{
    int i = blockIdx.x;
    int tid = threadIdx.x; // f = tid, 128 threads
    int h = tid >> 4;
    float acc[M_TOT];
    #pragma unroll
    for (int m = 0; m < M_TOT; ++m) acc[m] = 0.f;
    int pstart = row_start[i], pend = row_start[i + 1];
    __shared__ float al[8][NDH];
    __shared__ float sl[8][M_TOT];
    __shared__ float xml[8];
    __shared__ int   jl[8];
    for (int pc = pstart; pc < pend; pc += 8) {
        int nb = min(8, pend - pc);
        __syncthreads();
        for (int e = tid; e < nb * NDH; e += 128)
            al[e / NDH][e % NDH] = alpha[(size_t)(pc + e / NDH) * NDH + e % NDH];
        for (int e = tid; e < nb * M_TOT; e += 128)
            sl[e / M_TOT][e % M_TOT] = sph[(size_t)(pc + e / M_TOT) * M_TOT + e % M_TOT];
        if (tid < nb) { xml[tid] = mask[pc + tid]; jl[tid] = idx_j[pc + tid]; }
        __syncthreads();
        for (int q = 0; q < nb; ++q) {
            int j = jl[q];
            float xv = x[(size_t)j * F + tid] * xml[q];
            float c0 = al[q][0 + h], c1 = al[q][8 + h], c2 = al[q][16 + h];
            #pragma unroll
            for (int m = 0; m < 3; ++m)  acc[m] += c0 * sl[q][m] * xv;
            #pragma unroll
            for (int m = 3; m < 8; ++m)  acc[m] += c1 * sl[q][m] * xv;
            #pragma unroll
            for (int m = 8; m < 15; ++m) acc[m] += c2 * sl[q][m] * xv;
        }
    }
    size_t ob = (size_t)i * (M_TOT * F) + tid;
    #pragma unroll
    for (int m = 0; m < M_TOT; ++m) out[ob + m * F] = acc[m];
}

extern "C" void kernel_launch(void* const* d_in, const int* in_sizes, int n_in,
                              void* d_out, int out_size, void* d_ws, size_t ws_size,
                              hipStream_t stream) {
    const float* x     = (const float*)d_in[0];
    const float* rbf   = (const float*)d_in[1];
    const float* sph   = (const float*)d_in[2];
    const float* phi   = (const float*)d_in[3];
    const int*   idx_i = (const int*)d_in[4];
    const int*   idx_j = (const int*)d_in[5];
    const float* mask  = (const float*)d_in[6];
    const float* WQ    = (const float*)d_in[7];
    const float* WK    = (const float*)d_in[8];
    const float* av    = (const float*)d_in[9];
    const float* W1    = (const float*)d_in[10];
    const float* b1    = (const float*)d_in[11];
    const float* W2    = (const float*)d_in[12];
    const float* b2    = (const float*)d_in[13];
    float* out = (float*)d_out;
    char* ws = (char*)d_ws;

    // ws layout (bytes):
    // Gq  bf16 [0,        25165824)
    // Gk  bf16 [25165824, 50331648)
    // bq  f32  [50331648, 51118080)
    // bk  f32  [51118080, 51904512)
    // row_start [51904512, 51937536)
    // counts    [51937536, 51970304)
    // offsets   [51970304, 52003840)   (8193 ints)
    // cnt2      [52003840, 52036608)
    // sorted    [52036608, 52560896)
    // h1  bf16  [52560896, 69338112)
    // alpha f32 [69338112, 81921024)   -- Wc/bc alias its head (dead before alpha_q2)
    __hip_bfloat16* Gq = (__hip_bfloat16*)(ws + 0);
    __hip_bfloat16* Gk = (__hip_bfloat16*)(ws + 25165824);
    float* bq = (float*)(ws + 50331648);
    float* bk = (float*)(ws + 51118080);
    int* row_start = (int*)(ws + 51904512);
    int* counts    = (int*)(ws + 51937536);
    int* offsets   = (int*)(ws + 51970304);
    int* cnt2      = (int*)(ws + 52003840);
    int* sorted    = (int*)(ws + 52036608);
    unsigned short* h1 = (unsigned short*)(ws + 52560896);
    float* alphaBuf = (float*)(ws + 69338112);
    float* Wc = (float*)(ws + 69338112);           // 196608 B, dead before alpha_q2
    float* bc = (float*)(ws + 69338112 + 196608);  // 6144 B

    k_zero<<<(N_ATOMS + 255) / 256, 256, 0, stream>>>(counts, cnt2);
    k_seg<<<(N_PAIR + 255) / 256, 256, 0, stream>>>(idx_i, row_start);
    k_hist<<<(N_PAIR + 255) / 256, 256, 0, stream>>>(idx_j, counts);
    k_scan<<<1, 1024, 0, stream>>>(counts, offsets);
    k_place<<<(N_PAIR + 255) / 256, 256, 0, stream>>>(idx_j, offsets, cnt2, sorted);
    k_wc<<<48, 256, 0, stream>>>(WQ, WK, av, W2, b2, Wc, bc);
    k_gfused<<<dim3(N_ATOMS / 64, 48), 256, 0, stream>>>(x, Wc, bc, Gq, Gk, bq, bk);
    k_h1<<<N_PAIR / 64, 256, 0, stream>>>(rbf, W1, b1, h1);
    k_alpha_q2<<<N_PAIR / 64, 256, 0, stream>>>(idx_i, h1, Gq, bq, alphaBuf);
    k_alpha_k2<<<N_PAIR / 64, 256, 0, stream>>>(sorted, idx_j, h1, Gk, bk, phi, mask, alphaBuf);
    k_aggr<<<N_ATOMS, 128, 0, stream>>>(x, sph, mask, idx_j, alphaBuf, row_start, out);
}

// Round 6
// 221.886 us; speedup vs baseline: 1.5345x; 1.0025x over previous
//
#include <hip/hip_runtime.h>
#include <hip/hip_bf16.h>

#define N_ATOMS 8192
#define N_PAIR  131072
#define F       128
#define N_HEAD  8
#define FH      16
#define N_DEG   3
#define M_TOT   15
#define K_RBF   32
#define H_FILT  64
#define FILT_OUT 768
#define NDH     24   // N_DEG * N_HEAD

typedef __attribute__((ext_vector_type(8))) unsigned short u16x8;

__device__ __forceinline__ float bf2f(unsigned short u) {
    return __uint_as_float(((unsigned)u) << 16);
}
__device__ __forceinline__ unsigned short f2bfbits(float f) {
    __hip_bfloat16 b = __float2bfloat16(f);
    return *reinterpret_cast<unsigned short*>(&b);
}

// ---------------- K0: segment starts (idx_i is sorted) ----------------
__global__ void k_seg(const int* __restrict__ idx_i, int* __restrict__ row_start) {
    int p = blockIdx.x * 256 + threadIdx.x;
    if (p >= N_PAIR) return;
    int ii = idx_i[p];
    int prev = (p == 0) ? -1 : idx_i[p - 1];
    for (int a = prev + 1; a <= ii; ++a) row_start[a] = p;
    if (p == N_PAIR - 1) {
        for (int a = ii + 1; a <= N_ATOMS; ++a) row_start[a] = N_PAIR;
    }
}

// ---------------- zero counters (graph-replay safe) ----------------
__global__ void k_zero(int* __restrict__ counts, int* __restrict__ cnt2) {
    int t = blockIdx.x * 256 + threadIdx.x;
    if (t < N_ATOMS) { counts[t] = 0; cnt2[t] = 0; }
}

// ---------------- histogram of idx_j ----------------
__global__ void k_hist(const int* __restrict__ idx_j, int* __restrict__ counts) {
    int p = blockIdx.x * 256 + threadIdx.x;
    if (p < N_PAIR) atomicAdd(&counts[idx_j[p]], 1);
}

// ---------------- exclusive scan of 8192 counts (1 block) ----------------
__global__ __launch_bounds__(1024) void k_scan(const int* __restrict__ counts,
                                               int* __restrict__ offsets) {
    __shared__ int ts[1024];
    int tid = threadIdx.x;
    int base = tid * 8;
    int v[8]; int tot = 0;
    #pragma unroll
    for (int q = 0; q < 8; ++q) { v[q] = counts[base + q]; tot += v[q]; }
    ts[tid] = tot; __syncthreads();
    for (int off = 1; off < 1024; off <<= 1) {
        int t2 = (tid >= off) ? ts[tid - off] : 0;
        __syncthreads();
        ts[tid] += t2;
        __syncthreads();
    }
    int excl = ts[tid] - tot;
    #pragma unroll
    for (int q = 0; q < 8; ++q) { offsets[base + q] = excl; excl += v[q]; }
    if (tid == 1023) offsets[N_ATOMS] = ts[1023];
}

// ---------------- placement: sorted pair ids per j-bucket + rank ----------------
__global__ void k_place(const int* __restrict__ idx_j, const int* __restrict__ offsets,
                        int* __restrict__ cnt2, int* __restrict__ sorted,
                        int* __restrict__ rank) {
    int p = blockIdx.x * 256 + threadIdx.x;
    if (p < N_PAIR) {
        int j = idx_j[p];
        int pos = offsets[j] + atomicAdd(&cnt2[j], 1);
        sorted[pos] = p;
        rank[p] = pos;
    }
}

// ---------------- K_wc: combined weights ----------------
__global__ __launch_bounds__(256) void k_wc(
    const float* __restrict__ WQ, const float* __restrict__ WK,
    const float* __restrict__ avec, const float* __restrict__ W2,
    const float* __restrict__ b2,
    float* __restrict__ Wc, float* __restrict__ bc)
{
    int bx = blockIdx.x;             // 0..47
    int side = bx / NDH, dh = bx % NDH;
    int d = dh >> 3, h = dh & 7;
    int colbase = d * 256 + h * 32 + side * 16;
    const float* W = (side == 0) ? WQ : WK;
    __shared__ float w2s[64][16];
    __shared__ float ws[16][16];     // W[d][h][c][j]
    __shared__ float as[16];
    __shared__ float b2s[16];
    int tid = threadIdx.x;
    for (int e = tid; e < 64 * 16; e += 256)
        w2s[e >> 4][e & 15] = W2[(e >> 4) * FILT_OUT + colbase + (e & 15)];
    if (tid < 16 * 16) ws[tid >> 4][tid & 15] = W[((d * 8 + h) * 16) * 16 + tid];
    if (tid < 16) { as[tid] = avec[dh * 32 + side * 16 + tid]; b2s[tid] = b2[colbase + tid]; }
    __syncthreads();
    for (int o = tid; o < 64 * 16; o += 256) {
        int k = o >> 4, j = o & 15;
        float s = 0.f;
        #pragma unroll
        for (int c = 0; c < 16; ++c) s += w2s[k][c] * as[c] * ws[c][j];
        Wc[((size_t)bx * 64 + k) * 16 + j] = s;
    }
    if (tid < 16) {
        float s = 0.f;
        #pragma unroll
        for (int c = 0; c < 16; ++c) s += b2s[c] * as[c] * ws[c][tid];
        bc[bx * 16 + tid] = s;
    }
}

// ---------------- K_gfused: x -> Gq/Gk/bq/bk directly ----------------
__global__ __launch_bounds__(256) void k_gfused(
    const float* __restrict__ x, const float* __restrict__ Wc,
    const float* __restrict__ bc,
    __hip_bfloat16* __restrict__ Gq, __hip_bfloat16* __restrict__ Gk,
    float* __restrict__ bq, float* __restrict__ bk)
{
    int bx = blockIdx.x;             // 128 blocks of 64 atoms
    int by = blockIdx.y;             // 0..47: side, dh
    int side = by / NDH, dh = by % NDH;
    int h = dh & 7;
    int n0 = bx * 64;
    __shared__ float xh[64][17];     // padded: conflict-free per-at reads
    __shared__ float bcs[16];
    int tid = threadIdx.x;
    for (int e = tid; e < 64 * 16; e += 256)
        xh[e >> 4][e & 15] = x[(size_t)(n0 + (e >> 4)) * F + h * 16 + (e & 15)];
    if (tid < 16) bcs[tid] = bc[by * 16 + tid];
    int k = tid & 63, wv = tid >> 6;
    float wcr[16];
    const float* wp = Wc + ((size_t)by * 64 + k) * 16;
    #pragma unroll
    for (int j = 0; j < 16; ++j) wcr[j] = wp[j];
    __syncthreads();
    __hip_bfloat16* G = (side == 0) ? Gq : Gk;
    #pragma unroll 4
    for (int it = 0; it < 16; ++it) {
        int at = wv * 16 + it;
        float acc = 0.f;
        #pragma unroll
        for (int j = 0; j < 16; ++j) acc += wcr[j] * xh[at][j];  // broadcast reads
        G[(size_t)(n0 + at) * 1536 + dh * 64 + k] = __float2bfloat16(acc);
    }
    if (tid < 64) {
        float* B = (side == 0) ? bq : bk;
        float s = 0.f;
        #pragma unroll
        for (int j = 0; j < 16; ++j) s += bcs[j] * xh[tid][j];
        B[(n0 + tid) * NDH + dh] = s;
    }
}

// ---------------- K2a: h1[p,64] = silu(rbf @ W1 + b1), bf16 ----------------
__global__ __launch_bounds__(256) void k_h1(
    const float* __restrict__ rbf, const float* __restrict__ W1,
    const float* __restrict__ b1, unsigned short* __restrict__ h1)
{
    __shared__ float w1s[K_RBF][H_FILT]; // 8 KB
    __shared__ float b1s[H_FILT];
    __shared__ float rbfs[64][33];       // padded
    int tid = threadIdx.x;
    int p0 = blockIdx.x * 64;
    for (int e = tid; e < K_RBF * H_FILT; e += 256) w1s[e >> 6][e & 63] = W1[e];
    if (tid < H_FILT) b1s[tid] = b1[tid];
    for (int e = tid; e < 64 * K_RBF; e += 256)
        rbfs[e >> 5][e & 31] = rbf[(size_t)p0 * K_RBF + e];
    __syncthreads();
    int pp = tid >> 2;
    int kbase = (tid & 3) * 16;
    float acc[16];
    #pragma unroll
    for (int q = 0; q < 16; ++q) acc[q] = b1s[kbase + q];
    for (int c = 0; c < K_RBF; ++c) {
        float r = rbfs[pp][c];
        #pragma unroll
        for (int q = 0; q < 16; ++q) acc[q] += r * w1s[c][kbase + q];
    }
    u16x8 o0, o1;
    #pragma unroll
    for (int q = 0; q < 8; ++q) {
        float s0 = acc[q];     o0[q] = f2bfbits(s0 / (1.f + __expf(-s0)));
        float s1 = acc[q + 8]; o1[q] = f2bfbits(s1 / (1.f + __expf(-s1)));
    }
    unsigned short* hp = h1 + (size_t)(p0 + pp) * 64 + kbase;
    *reinterpret_cast<u16x8*>(hp) = o0;
    *reinterpret_cast<u16x8*>(hp + 8) = o1;
}

// ---------------- K2c: K-side alpha, software-pipelined, sequential bf16 output ----------------
// alphaKs[pos*24+dh] = dot(h1[sorted[pos]], Gk[idx_j[sorted[pos]], dh, :]) + bk
__global__ __launch_bounds__(256) void k_alphak(
    const int* __restrict__ sorted, const int* __restrict__ idx_j,
    const unsigned short* __restrict__ h1,
    const __hip_bfloat16* __restrict__ Gk, const float* __restrict__ bk,
    unsigned short* __restrict__ alphaKs)
{
    __shared__ unsigned short h1s[64][64]; // 8 KB
    __shared__ int ps[64];
    __shared__ int js[64];
    int tid = threadIdx.x;
    int c0 = blockIdx.x * 64;
    if (tid < 64) {
        int pid = sorted[c0 + tid];
        ps[tid] = pid;
        js[tid] = idx_j[pid];
    }
    __syncthreads();
    for (int e = tid; e < 64 * 8; e += 256) {
        int slot = e >> 3, seg = e & 7;
        *reinterpret_cast<u16x8*>(&h1s[slot][seg * 8]) =
            *reinterpret_cast<const u16x8*>(h1 + (size_t)ps[slot] * 64 + seg * 8);
    }
    __syncthreads();

    const unsigned short* GkU = reinterpret_cast<const unsigned short*>(Gk);
    unsigned sA, dA, sB, dB;
    const unsigned short* gA; const unsigned short* gB;
    float bkA, bkB;
    u16x8 vA[8], vB[8];

#define AK_ADDRLOAD(S, D, G, BK, V, T)                                   \
    { unsigned task = (T) * 256u + (unsigned)tid;                        \
      S = task / 24u; D = task - S * 24u;                                \
      int j_ = js[S];                                                    \
      G = GkU + (size_t)j_ * 1536 + D * 64;                              \
      BK = bk[j_ * NDH + D];                                             \
      _Pragma("unroll")                                                  \
      for (int v = 0; v < 8; ++v) V[v] = *reinterpret_cast<const u16x8*>(G + v * 8); }

#define AK_COMP(S, BK, V, T)                                             \
    { float a0 = 0.f, a1 = 0.f, a2 = 0.f, a3 = 0.f;                      \
      _Pragma("unroll")                                                  \
      for (int v = 0; v < 8; ++v) {                                      \
        u16x8 hv = *reinterpret_cast<const u16x8*>(&h1s[S][v * 8]);      \
        a0 += bf2f(V[v][0]) * bf2f(hv[0]);                               \
        a1 += bf2f(V[v][1]) * bf2f(hv[1]);                               \
        a2 += bf2f(V[v][2]) * bf2f(hv[2]);                               \
        a3 += bf2f(V[v][3]) * bf2f(hv[3]);                               \
        a0 += bf2f(V[v][4]) * bf2f(hv[4]);                               \
        a1 += bf2f(V[v][5]) * bf2f(hv[5]);                               \
        a2 += bf2f(V[v][6]) * bf2f(hv[6]);                               \
        a3 += bf2f(V[v][7]) * bf2f(hv[7]);                               \
      }                                                                  \
      alphaKs[(size_t)c0 * 24 + (T) * 256 + tid] =                       \
          f2bfbits(BK + (a0 + a1) + (a2 + a3)); }

    AK_ADDRLOAD(sA, dA, gA, bkA, vA, 0);
    AK_ADDRLOAD(sB, dB, gB, bkB, vB, 1); AK_COMP(sA, bkA, vA, 0);
    AK_ADDRLOAD(sA, dA, gA, bkA, vA, 2); AK_COMP(sB, bkB, vB, 1);
    AK_ADDRLOAD(sB, dB, gB, bkB, vB, 3); AK_COMP(sA, bkA, vA, 2);
    AK_ADDRLOAD(sA, dA, gA, bkA, vA, 4); AK_COMP(sB, bkB, vB, 3);
    AK_ADDRLOAD(sB, dB, gB, bkB, vB, 5); AK_COMP(sA, bkA, vA, 4);
    AK_COMP(sB, bkB, vB, 5);
#undef AK_ADDRLOAD
#undef AK_COMP
}

// ---------------- K3: per-atom aggregation with fused Q-side alpha ----------------
__global__ __launch_bounds__(256) void k_aggr2(
    const float* __restrict__ x, const float* __restrict__ sph,
    const float* __restrict__ phi, const float* __restrict__ mask,
    const int* __restrict__ idx_j, const int* __restrict__ rank,
    const unsigned short* __restrict__ h1,
    const __hip_bfloat16* __restrict__ Gq, const float* __restrict__ bq,
    const unsigned short* __restrict__ alphaKs,
    const int* __restrict__ row_start, float* __restrict__ out)
{
    int i = blockIdx.x;
    int tid = threadIdx.x;
    int f = tid & 127;
    int grp = tid >> 7;          // 0/1: pair-group
    int h = f >> 4;              // head 0..7
    const unsigned short* gqrow = reinterpret_cast<const unsigned short*>(Gq) + (size_t)i * 1536;

    __shared__ unsigned short h1s[16][64];  // 2 KB
    __shared__ float als[16][24];           // 1.5 KB
    __shared__ float sls[16][15];
    __shared__ float bqs[24];
    __shared__ float pms[16];
    __shared__ float xms[16];
    __shared__ int jls[16];
    __shared__ int rks[16];
    __shared__ float red[M_TOT][128];       // 7.7 KB

    if (tid < 24) bqs[tid] = bq[i * NDH + tid];
    int pstart = row_start[i], pend = row_start[i + 1];

    float acc[M_TOT];
    #pragma unroll
    for (int m = 0; m < M_TOT; ++m) acc[m] = 0.f;

    for (int pc = pstart; pc < pend; pc += 16) {
        int nb = min(16, pend - pc);
        __syncthreads();
        if (tid < nb) {
            int p = pc + tid;
            jls[tid] = idx_j[p];
            rks[tid] = rank[p];
            pms[tid] = phi[p] * mask[p] * 0.25f;
            xms[tid] = mask[p];
        }
        for (int e = tid; e < nb * 8; e += 256) {
            int q = e >> 3, seg = e & 7;
            *reinterpret_cast<u16x8*>(&h1s[q][seg * 8]) =
                *reinterpret_cast<const u16x8*>(h1 + (size_t)(pc + q) * 64 + seg * 8);
        }
        for (int e = tid; e < nb * M_TOT; e += 256)
            sls[e / M_TOT][e % M_TOT] = sph[(size_t)(pc + e / M_TOT) * M_TOT + e % M_TOT];
        __syncthreads();
        // Q-side dot + combine with K-side: nb*24 tasks
        for (int e = tid; e < nb * 24; e += 256) {
            int q = e / 24, dh = e - q * 24;
            const unsigned short* gq = gqrow + dh * 64;
            u16x8 qv[8];
            #pragma unroll
            for (int v = 0; v < 8; ++v) qv[v] = *reinterpret_cast<const u16x8*>(gq + v * 8);
            float aks = bf2f(alphaKs[(size_t)rks[q] * 24 + dh]);
            float a0 = 0.f, a1 = 0.f, a2 = 0.f, a3 = 0.f;
            #pragma unroll
            for (int v = 0; v < 8; ++v) {
                u16x8 hv = *reinterpret_cast<const u16x8*>(&h1s[q][v * 8]);
                a0 += bf2f(qv[v][0]) * bf2f(hv[0]);
                a1 += bf2f(qv[v][1]) * bf2f(hv[1]);
                a2 += bf2f(qv[v][2]) * bf2f(hv[2]);
                a3 += bf2f(qv[v][3]) * bf2f(hv[3]);
                a0 += bf2f(qv[v][4]) * bf2f(hv[4]);
                a1 += bf2f(qv[v][5]) * bf2f(hv[5]);
                a2 += bf2f(qv[v][6]) * bf2f(hv[6]);
                a3 += bf2f(qv[v][7]) * bf2f(hv[7]);
            }
            als[q][dh] = ((a0 + a1) + (a2 + a3) + bqs[dh] + aks) * pms[q];
        }
        __syncthreads();
        // accumulate: group grp handles q = grp, grp+2, ...
        #pragma unroll
        for (int q2 = 0; q2 < 8; ++q2) {
            int q = q2 * 2 + grp;
            if (q < nb) {
                float xv = x[(size_t)jls[q] * F + f] * xms[q];
                float c0 = als[q][0 + h], c1 = als[q][8 + h], c2 = als[q][16 + h];
                #pragma unroll
                for (int m = 0; m < 3; ++m)  acc[m] += c0 * sls[q][m] * xv;
                #pragma unroll
                for (int m = 3; m < 8; ++m)  acc[m] += c1 * sls[q][m] * xv;
                #pragma unroll
                for (int m = 8; m < 15; ++m) acc[m] += c2 * sls[q][m] * xv;
            }
        }
    }
    __syncthreads();
    if (grp == 1) {
        #pragma unroll
        for (int m = 0; m < M_TOT; ++m) red[m][f] = acc[m];
    }
    __syncthreads();
    if (grp == 0) {
        size_t ob = (size_t)i * (M_TOT * F) + f;
        #pragma unroll
        for (int m = 0; m < M_TOT; ++m) out[ob + m * F] = acc[m] + red[m][f];
    }
}

extern "C" void kernel_launch(void* const* d_in, const int* in_sizes, int n_in,
                              void* d_out, int out_size, void* d_ws, size_t ws_size,
                              hipStream_t stream) {
    const float* x     = (const float*)d_in[0];
    const float* rbf   = (const float*)d_in[1];
    const float* sph   = (const float*)d_in[2];
    const float* phi   = (const float*)d_in[3];
    const int*   idx_i = (const int*)d_in[4];
    const int*   idx_j = (const int*)d_in[5];
    const float* mask  = (const float*)d_in[6];
    const float* WQ    = (const float*)d_in[7];
    const float* WK    = (const float*)d_in[8];
    const float* av    = (const float*)d_in[9];
    const float* W1    = (const float*)d_in[10];
    const float* b1    = (const float*)d_in[11];
    const float* W2    = (const float*)d_in[12];
    const float* b2    = (const float*)d_in[13];
    float* out = (float*)d_out;
    char* ws = (char*)d_ws;

    // ws layout (bytes):
    // Gq   bf16 [0,        25165824)
    // Gk   bf16 [25165824, 50331648)
    // bq   f32  [50331648, 51118080)
    // bk   f32  [51118080, 51904512)
    // row_start [51904512, 51937792)   (8193 ints, padded)
    // counts    [51937792, 51970560)
    // offsets   [51970560, 52003840)   (8193 ints, padded)
    // cnt2      [52003840, 52036608)
    // sorted    [52036608, 52560896)
    // rank      [52560896, 53085184)
    // h1   bf16 [53085184, 69862400)
    // alphaKs bf16 [69862400, 76153856)
    // Wc   f32  [76153856, 76350464)
    // bc   f32  [76350464, 76356608)
    __hip_bfloat16* Gq = (__hip_bfloat16*)(ws + 0);
    __hip_bfloat16* Gk = (__hip_bfloat16*)(ws + 25165824);
    float* bq = (float*)(ws + 50331648);
    float* bk = (float*)(ws + 51118080);
    int* row_start = (int*)(ws + 51904512);
    int* counts    = (int*)(ws + 51937792);
    int* offsets   = (int*)(ws + 51970560);
    int* cnt2      = (int*)(ws + 52003840);
    int* sorted    = (int*)(ws + 52036608);
    int* rank      = (int*)(ws + 52560896);
    unsigned short* h1      = (unsigned short*)(ws + 53085184);
    unsigned short* alphaKs = (unsigned short*)(ws + 69862400);
    float* Wc = (float*)(ws + 76153856);
    float* bc = (float*)(ws + 76350464);

    k_zero<<<(N_ATOMS + 255) / 256, 256, 0, stream>>>(counts, cnt2);
    k_seg<<<(N_PAIR + 255) / 256, 256, 0, stream>>>(idx_i, row_start);
    k_hist<<<(N_PAIR + 255) / 256, 256, 0, stream>>>(idx_j, counts);
    k_scan<<<1, 1024, 0, stream>>>(counts, offsets);
    k_place<<<(N_PAIR + 255) / 256, 256, 0, stream>>>(idx_j, offsets, cnt2, sorted, rank);
    k_wc<<<48, 256, 0, stream>>>(WQ, WK, av, W2, b2, Wc, bc);
    k_gfused<<<dim3(N_ATOMS / 64, 48), 256, 0, stream>>>(x, Wc, bc, Gq, Gk, bq, bk);
    k_h1<<<N_PAIR / 64, 256, 0, stream>>>(rbf, W1, b1, h1);
    k_alphak<<<N_PAIR / 64, 256, 0, stream>>>(sorted, idx_j, h1, Gk, bk, alphaKs);
    k_aggr2<<<N_ATOMS, 256, 0, stream>>>(x, sph, phi, mask, idx_j, rank, h1, Gq, bq,
                                         alphaKs, row_start, out);
}

// Round 7
// 199.329 us; speedup vs baseline: 1.7082x; 1.1132x over previous
//
#include <hip/hip_runtime.h>
#include <hip/hip_bf16.h>

#define N_ATOMS 8192
#define N_PAIR  131072
#define F       128
#define N_HEAD  8
#define FH      16
#define N_DEG   3
#define M_TOT   15
#define K_RBF   32
#define H_FILT  64
#define FILT_OUT 768
#define NDH     24   // N_DEG * N_HEAD

typedef __attribute__((ext_vector_type(8))) unsigned short u16x8;

__device__ __forceinline__ float bf2f(unsigned short u) {
    return __uint_as_float(((unsigned)u) << 16);
}
__device__ __forceinline__ unsigned short f2bfbits(float f) {
    __hip_bfloat16 b = __float2bfloat16(f);
    return *reinterpret_cast<unsigned short*>(&b);
}

// ---------------- K0: segment starts (idx_i is sorted) ----------------
__global__ void k_seg(const int* __restrict__ idx_i, int* __restrict__ row_start) {
    int p = blockIdx.x * 256 + threadIdx.x;
    if (p >= N_PAIR) return;
    int ii = idx_i[p];
    int prev = (p == 0) ? -1 : idx_i[p - 1];
    for (int a = prev + 1; a <= ii; ++a) row_start[a] = p;
    if (p == N_PAIR - 1) {
        for (int a = ii + 1; a <= N_ATOMS; ++a) row_start[a] = N_PAIR;
    }
}

// ---------------- zero counters (graph-replay safe) ----------------
__global__ void k_zero(int* __restrict__ counts, int* __restrict__ cnt2) {
    int t = blockIdx.x * 256 + threadIdx.x;
    if (t < N_ATOMS) { counts[t] = 0; cnt2[t] = 0; }
}

// ---------------- histogram of idx_j ----------------
__global__ void k_hist(const int* __restrict__ idx_j, int* __restrict__ counts) {
    int p = blockIdx.x * 256 + threadIdx.x;
    if (p < N_PAIR) atomicAdd(&counts[idx_j[p]], 1);
}

// ---------------- exclusive scan of 8192 counts (1 block) ----------------
__global__ __launch_bounds__(1024) void k_scan(const int* __restrict__ counts,
                                               int* __restrict__ offsets) {
    __shared__ int ts[1024];
    int tid = threadIdx.x;
    int base = tid * 8;
    int v[8]; int tot = 0;
    #pragma unroll
    for (int q = 0; q < 8; ++q) { v[q] = counts[base + q]; tot += v[q]; }
    ts[tid] = tot; __syncthreads();
    for (int off = 1; off < 1024; off <<= 1) {
        int t2 = (tid >= off) ? ts[tid - off] : 0;
        __syncthreads();
        ts[tid] += t2;
        __syncthreads();
    }
    int excl = ts[tid] - tot;
    #pragma unroll
    for (int q = 0; q < 8; ++q) { offsets[base + q] = excl; excl += v[q]; }
    if (tid == 1023) offsets[N_ATOMS] = ts[1023];
}

// ---------------- placement: sorted pair ids per j-bucket + rank ----------------
__global__ void k_place(const int* __restrict__ idx_j, const int* __restrict__ offsets,
                        int* __restrict__ cnt2, int* __restrict__ sorted,
                        int* __restrict__ rank) {
    int p = blockIdx.x * 256 + threadIdx.x;
    if (p < N_PAIR) {
        int j = idx_j[p];
        int pos = offsets[j] + atomicAdd(&cnt2[j], 1);
        sorted[pos] = p;
        rank[p] = pos;
    }
}

// ---------------- K_wc: combined weights ----------------
__global__ __launch_bounds__(256) void k_wc(
    const float* __restrict__ WQ, const float* __restrict__ WK,
    const float* __restrict__ avec, const float* __restrict__ W2,
    const float* __restrict__ b2,
    float* __restrict__ Wc, float* __restrict__ bc)
{
    int bx = blockIdx.x;             // 0..47
    int side = bx / NDH, dh = bx % NDH;
    int d = dh >> 3, h = dh & 7;
    int colbase = d * 256 + h * 32 + side * 16;
    const float* W = (side == 0) ? WQ : WK;
    __shared__ float w2s[64][16];
    __shared__ float ws[16][16];     // W[d][h][c][j]
    __shared__ float as[16];
    __shared__ float b2s[16];
    int tid = threadIdx.x;
    for (int e = tid; e < 64 * 16; e += 256)
        w2s[e >> 4][e & 15] = W2[(e >> 4) * FILT_OUT + colbase + (e & 15)];
    if (tid < 16 * 16) ws[tid >> 4][tid & 15] = W[((d * 8 + h) * 16) * 16 + tid];
    if (tid < 16) { as[tid] = avec[dh * 32 + side * 16 + tid]; b2s[tid] = b2[colbase + tid]; }
    __syncthreads();
    for (int o = tid; o < 64 * 16; o += 256) {
        int k = o >> 4, j = o & 15;
        float s = 0.f;
        #pragma unroll
        for (int c = 0; c < 16; ++c) s += w2s[k][c] * as[c] * ws[c][j];
        Wc[((size_t)bx * 64 + k) * 16 + j] = s;
    }
    if (tid < 16) {
        float s = 0.f;
        #pragma unroll
        for (int c = 0; c < 16; ++c) s += b2s[c] * as[c] * ws[c][tid];
        bc[bx * 16 + tid] = s;
    }
}

// ---------------- K_gfused: x -> Gq/Gk/bq/bk directly ----------------
__global__ __launch_bounds__(256) void k_gfused(
    const float* __restrict__ x, const float* __restrict__ Wc,
    const float* __restrict__ bc,
    __hip_bfloat16* __restrict__ Gq, __hip_bfloat16* __restrict__ Gk,
    float* __restrict__ bq, float* __restrict__ bk)
{
    int bx = blockIdx.x;             // 128 blocks of 64 atoms
    int by = blockIdx.y;             // 0..47: side, dh
    int side = by / NDH, dh = by % NDH;
    int h = dh & 7;
    int n0 = bx * 64;
    __shared__ float xh[64][17];     // padded: conflict-free per-at reads
    __shared__ float bcs[16];
    int tid = threadIdx.x;
    for (int e = tid; e < 64 * 16; e += 256)
        xh[e >> 4][e & 15] = x[(size_t)(n0 + (e >> 4)) * F + h * 16 + (e & 15)];
    if (tid < 16) bcs[tid] = bc[by * 16 + tid];
    int k = tid & 63, wv = tid >> 6;
    float wcr[16];
    const float* wp = Wc + ((size_t)by * 64 + k) * 16;
    #pragma unroll
    for (int j = 0; j < 16; ++j) wcr[j] = wp[j];
    __syncthreads();
    __hip_bfloat16* G = (side == 0) ? Gq : Gk;
    #pragma unroll 4
    for (int it = 0; it < 16; ++it) {
        int at = wv * 16 + it;
        float acc = 0.f;
        #pragma unroll
        for (int j = 0; j < 16; ++j) acc += wcr[j] * xh[at][j];  // broadcast reads
        G[(size_t)(n0 + at) * 1536 + dh * 64 + k] = __float2bfloat16(acc);
    }
    if (tid < 64) {
        float* B = (side == 0) ? bq : bk;
        float s = 0.f;
        #pragma unroll
        for (int j = 0; j < 16; ++j) s += bcs[j] * xh[tid][j];
        B[(n0 + tid) * NDH + dh] = s;
    }
}

// ---------------- K2a: h1[p,64] = silu(rbf @ W1 + b1), bf16 ----------------
__global__ __launch_bounds__(256) void k_h1(
    const float* __restrict__ rbf, const float* __restrict__ W1,
    const float* __restrict__ b1, unsigned short* __restrict__ h1)
{
    __shared__ float w1s[K_RBF][H_FILT]; // 8 KB
    __shared__ float b1s[H_FILT];
    __shared__ float rbfs[64][33];       // padded
    int tid = threadIdx.x;
    int p0 = blockIdx.x * 64;
    for (int e = tid; e < K_RBF * H_FILT; e += 256) w1s[e >> 6][e & 63] = W1[e];
    if (tid < H_FILT) b1s[tid] = b1[tid];
    for (int e = tid; e < 64 * K_RBF; e += 256)
        rbfs[e >> 5][e & 31] = rbf[(size_t)p0 * K_RBF + e];
    __syncthreads();
    int pp = tid >> 2;
    int kbase = (tid & 3) * 16;
    float acc[16];
    #pragma unroll
    for (int q = 0; q < 16; ++q) acc[q] = b1s[kbase + q];
    for (int c = 0; c < K_RBF; ++c) {
        float r = rbfs[pp][c];
        #pragma unroll
        for (int q = 0; q < 16; ++q) acc[q] += r * w1s[c][kbase + q];
    }
    u16x8 o0, o1;
    #pragma unroll
    for (int q = 0; q < 8; ++q) {
        float s0 = acc[q];     o0[q] = f2bfbits(s0 / (1.f + __expf(-s0)));
        float s1 = acc[q + 8]; o1[q] = f2bfbits(s1 / (1.f + __expf(-s1)));
    }
    unsigned short* hp = h1 + (size_t)(p0 + pp) * 64 + kbase;
    *reinterpret_cast<u16x8*>(hp) = o0;
    *reinterpret_cast<u16x8*>(hp + 8) = o1;
}

// ---------------- K2c: K-side alpha, software-pipelined, sequential bf16 output ----------------
__global__ __launch_bounds__(256) void k_alphak(
    const int* __restrict__ sorted, const int* __restrict__ idx_j,
    const unsigned short* __restrict__ h1,
    const __hip_bfloat16* __restrict__ Gk, const float* __restrict__ bk,
    unsigned short* __restrict__ alphaKs)
{
    __shared__ unsigned short h1s[64][64]; // 8 KB
    __shared__ int ps[64];
    __shared__ int js[64];
    int tid = threadIdx.x;
    int c0 = blockIdx.x * 64;
    if (tid < 64) {
        int pid = sorted[c0 + tid];
        ps[tid] = pid;
        js[tid] = idx_j[pid];
    }
    __syncthreads();
    for (int e = tid; e < 64 * 8; e += 256) {
        int slot = e >> 3, seg = e & 7;
        *reinterpret_cast<u16x8*>(&h1s[slot][seg * 8]) =
            *reinterpret_cast<const u16x8*>(h1 + (size_t)ps[slot] * 64 + seg * 8);
    }
    __syncthreads();

    const unsigned short* GkU = reinterpret_cast<const unsigned short*>(Gk);
    unsigned sA, dA, sB, dB;
    const unsigned short* gA; const unsigned short* gB;
    float bkA, bkB;
    u16x8 vA[8], vB[8];

#define AK_ADDRLOAD(S, D, G, BK, V, T)                                   \
    { unsigned task = (T) * 256u + (unsigned)tid;                        \
      S = task / 24u; D = task - S * 24u;                                \
      int j_ = js[S];                                                    \
      G = GkU + (size_t)j_ * 1536 + D * 64;                              \
      BK = bk[j_ * NDH + D];                                             \
      _Pragma("unroll")                                                  \
      for (int v = 0; v < 8; ++v) V[v] = *reinterpret_cast<const u16x8*>(G + v * 8); }

#define AK_COMP(S, BK, V, T)                                             \
    { float a0 = 0.f, a1 = 0.f, a2 = 0.f, a3 = 0.f;                      \
      _Pragma("unroll")                                                  \
      for (int v = 0; v < 8; ++v) {                                      \
        u16x8 hv = *reinterpret_cast<const u16x8*>(&h1s[S][v * 8]);      \
        a0 += bf2f(V[v][0]) * bf2f(hv[0]);                               \
        a1 += bf2f(V[v][1]) * bf2f(hv[1]);                               \
        a2 += bf2f(V[v][2]) * bf2f(hv[2]);                               \
        a3 += bf2f(V[v][3]) * bf2f(hv[3]);                               \
        a0 += bf2f(V[v][4]) * bf2f(hv[4]);                               \
        a1 += bf2f(V[v][5]) * bf2f(hv[5]);                               \
        a2 += bf2f(V[v][6]) * bf2f(hv[6]);                               \
        a3 += bf2f(V[v][7]) * bf2f(hv[7]);                               \
      }                                                                  \
      alphaKs[(size_t)c0 * 24 + (T) * 256 + tid] =                       \
          f2bfbits(BK + (a0 + a1) + (a2 + a3)); }

    AK_ADDRLOAD(sA, dA, gA, bkA, vA, 0);
    AK_ADDRLOAD(sB, dB, gB, bkB, vB, 1); AK_COMP(sA, bkA, vA, 0);
    AK_ADDRLOAD(sA, dA, gA, bkA, vA, 2); AK_COMP(sB, bkB, vB, 1);
    AK_ADDRLOAD(sB, dB, gB, bkB, vB, 3); AK_COMP(sA, bkA, vA, 2);
    AK_ADDRLOAD(sA, dA, gA, bkA, vA, 4); AK_COMP(sB, bkB, vB, 3);
    AK_ADDRLOAD(sB, dB, gB, bkB, vB, 5); AK_COMP(sA, bkA, vA, 4);
    AK_COMP(sB, bkB, vB, 5);
#undef AK_ADDRLOAD
#undef AK_COMP
}

// ---------------- K3: per-atom aggregation, all-LDS inner loops ----------------
__global__ __launch_bounds__(256) void k_aggr3(
    const float* __restrict__ x, const float* __restrict__ sph,
    const float* __restrict__ phi, const float* __restrict__ mask,
    const int* __restrict__ idx_j, const int* __restrict__ rank,
    const unsigned short* __restrict__ h1,
    const __hip_bfloat16* __restrict__ Gq, const float* __restrict__ bq,
    const unsigned short* __restrict__ alphaKs,
    const int* __restrict__ row_start, float* __restrict__ out)
{
    int i = blockIdx.x;
    int tid = threadIdx.x;
    int f = tid & 127;
    int grp = tid >> 7;          // 0/1: pair-parity group
    int h = f >> 4;              // head 0..7

    __shared__ float xls[32][128];          // 16 KB; aliased as red[] in epilogue
    __shared__ unsigned short gqs[24][72];  // padded rows (144 B)
    __shared__ unsigned short h1s[32][72];  // padded rows (144 B)
    __shared__ float sls[32][15];
    __shared__ float als[32][24];
    __shared__ float bqs[24];
    __shared__ float pms[32];
    __shared__ float xms[32];
    __shared__ int rks[32];

    // stage this atom's Gq row (3 KB) once, coalesced
    const unsigned short* gqrow = reinterpret_cast<const unsigned short*>(Gq) + (size_t)i * 1536;
    for (int e = tid; e < 24 * 64; e += 256) gqs[e >> 6][e & 63] = gqrow[e];
    if (tid < 24) bqs[tid] = bq[i * NDH + tid];
    int pstart = row_start[i], pend = row_start[i + 1];

    float acc[M_TOT];
    #pragma unroll
    for (int m = 0; m < M_TOT; ++m) acc[m] = 0.f;

    for (int pc = pstart; pc < pend; pc += 32) {
        int nb = min(32, pend - pc);
        __syncthreads();
        if (tid < nb) {
            int p = pc + tid;
            rks[tid] = rank[p];
            pms[tid] = phi[p] * mask[p] * 0.25f;
            xms[tid] = mask[p];
        }
        // stage h1 rows (vector)
        for (int e = tid; e < nb * 8; e += 256) {
            int q = e >> 3, seg = e & 7;
            *reinterpret_cast<u16x8*>(&h1s[q][seg * 8]) =
                *reinterpret_cast<const u16x8*>(h1 + (size_t)(pc + q) * 64 + seg * 8);
        }
        // stage sph rows
        for (int e = tid; e < nb * M_TOT; e += 256)
            sls[e / M_TOT][e % M_TOT] = sph[(size_t)(pc + e / M_TOT) * M_TOT + e % M_TOT];
        // stage x rows cooperatively (float4, fully parallel)
        for (int e = tid; e < nb * 32; e += 256) {
            int q = e >> 5, c4 = e & 31;
            int j = idx_j[pc + q];
            *reinterpret_cast<float4*>(&xls[q][c4 * 4]) =
                *reinterpret_cast<const float4*>(x + (size_t)j * F + c4 * 4);
        }
        __syncthreads();
        // alpha phase: nb*24 tasks, all operands in LDS except alphaKs gather
        for (int e = tid; e < nb * 24; e += 256) {
            int q = e / 24, dh = e - q * 24;
            u16x8 qv[8];
            #pragma unroll
            for (int v = 0; v < 8; ++v) qv[v] = *reinterpret_cast<const u16x8*>(&gqs[dh][v * 8]);
            float aks = bf2f(alphaKs[(size_t)rks[q] * 24 + dh]);
            float a0 = 0.f, a1 = 0.f, a2 = 0.f, a3 = 0.f;
            #pragma unroll
            for (int v = 0; v < 8; ++v) {
                u16x8 hv = *reinterpret_cast<const u16x8*>(&h1s[q][v * 8]);
                a0 += bf2f(qv[v][0]) * bf2f(hv[0]);
                a1 += bf2f(qv[v][1]) * bf2f(hv[1]);
                a2 += bf2f(qv[v][2]) * bf2f(hv[2]);
                a3 += bf2f(qv[v][3]) * bf2f(hv[3]);
                a0 += bf2f(qv[v][4]) * bf2f(hv[4]);
                a1 += bf2f(qv[v][5]) * bf2f(hv[5]);
                a2 += bf2f(qv[v][6]) * bf2f(hv[6]);
                a3 += bf2f(qv[v][7]) * bf2f(hv[7]);
            }
            als[q][dh] = ((a0 + a1) + (a2 + a3) + bqs[dh] + aks) * pms[q];
        }
        __syncthreads();
        // accumulate phase: pure LDS + VALU
        #pragma unroll
        for (int q2 = 0; q2 < 16; ++q2) {
            int q = q2 * 2 + grp;
            if (q < nb) {
                float xv = xls[q][f] * xms[q];
                float c0 = als[q][0 + h], c1 = als[q][8 + h], c2 = als[q][16 + h];
                #pragma unroll
                for (int m = 0; m < 3; ++m)  acc[m] += c0 * sls[q][m] * xv;
                #pragma unroll
                for (int m = 3; m < 8; ++m)  acc[m] += c1 * sls[q][m] * xv;
                #pragma unroll
                for (int m = 8; m < 15; ++m) acc[m] += c2 * sls[q][m] * xv;
            }
        }
    }
    __syncthreads();
    float* red = &xls[0][0];     // alias: xls dead after last chunk
    if (grp == 1) {
        #pragma unroll
        for (int m = 0; m < M_TOT; ++m) red[m * 128 + f] = acc[m];
    }
    __syncthreads();
    if (grp == 0) {
        size_t ob = (size_t)i * (M_TOT * F) + f;
        #pragma unroll
        for (int m = 0; m < M_TOT; ++m) out[ob + m * F] = acc[m] + red[m * 128 + f];
    }
}

extern "C" void kernel_launch(void* const* d_in, const int* in_sizes, int n_in,
                              void* d_out, int out_size, void* d_ws, size_t ws_size,
                              hipStream_t stream) {
    const float* x     = (const float*)d_in[0];
    const float* rbf   = (const float*)d_in[1];
    const float* sph   = (const float*)d_in[2];
    const float* phi   = (const float*)d_in[3];
    const int*   idx_i = (const int*)d_in[4];
    const int*   idx_j = (const int*)d_in[5];
    const float* mask  = (const float*)d_in[6];
    const float* WQ    = (const float*)d_in[7];
    const float* WK    = (const float*)d_in[8];
    const float* av    = (const float*)d_in[9];
    const float* W1    = (const float*)d_in[10];
    const float* b1    = (const float*)d_in[11];
    const float* W2    = (const float*)d_in[12];
    const float* b2    = (const float*)d_in[13];
    float* out = (float*)d_out;
    char* ws = (char*)d_ws;

    // ws layout (bytes):
    // Gq   bf16 [0,        25165824)
    // Gk   bf16 [25165824, 50331648)
    // bq   f32  [50331648, 51118080)
    // bk   f32  [51118080, 51904512)
    // row_start [51904512, 51937792)   (8193 ints, padded)
    // counts    [51937792, 51970560)
    // offsets   [51970560, 52003840)   (8193 ints, padded)
    // cnt2      [52003840, 52036608)
    // sorted    [52036608, 52560896)
    // rank      [52560896, 53085184)
    // h1   bf16 [53085184, 69862400)
    // alphaKs bf16 [69862400, 76153856)
    // Wc   f32  [76153856, 76350464)
    // bc   f32  [76350464, 76356608)
    __hip_bfloat16* Gq = (__hip_bfloat16*)(ws + 0);
    __hip_bfloat16* Gk = (__hip_bfloat16*)(ws + 25165824);
    float* bq = (float*)(ws + 50331648);
    float* bk = (float*)(ws + 51118080);
    int* row_start = (int*)(ws + 51904512);
    int* counts    = (int*)(ws + 51937792);
    int* offsets   = (int*)(ws + 51970560);
    int* cnt2      = (int*)(ws + 52003840);
    int* sorted    = (int*)(ws + 52036608);
    int* rank      = (int*)(ws + 52560896);
    unsigned short* h1      = (unsigned short*)(ws + 53085184);
    unsigned short* alphaKs = (unsigned short*)(ws + 69862400);
    float* Wc = (float*)(ws + 76153856);
    float* bc = (float*)(ws + 76350464);

    k_zero<<<(N_ATOMS + 255) / 256, 256, 0, stream>>>(counts, cnt2);
    k_seg<<<(N_PAIR + 255) / 256, 256, 0, stream>>>(idx_i, row_start);
    k_hist<<<(N_PAIR + 255) / 256, 256, 0, stream>>>(idx_j, counts);
    k_scan<<<1, 1024, 0, stream>>>(counts, offsets);
    k_place<<<(N_PAIR + 255) / 256, 256, 0, stream>>>(idx_j, offsets, cnt2, sorted, rank);
    k_wc<<<48, 256, 0, stream>>>(WQ, WK, av, W2, b2, Wc, bc);
    k_gfused<<<dim3(N_ATOMS / 64, 48), 256, 0, stream>>>(x, Wc, bc, Gq, Gk, bq, bk);
    k_h1<<<N_PAIR / 64, 256, 0, stream>>>(rbf, W1, b1, h1);
    k_alphak<<<N_PAIR / 64, 256, 0, stream>>>(sorted, idx_j, h1, Gk, bk, alphaKs);
    k_aggr3<<<N_ATOMS, 256, 0, stream>>>(x, sph, phi, mask, idx_j, rank, h1, Gq, bq,
                                         alphaKs, row_start, out);
}